// Round 5
// baseline (721.835 us; speedup 1.0000x reference)
//
#include <hip/hip_runtime.h>
#include <stdint.h>
#include <math.h>

typedef unsigned int u32;
typedef __attribute__((ext_vector_type(8))) short short8;
typedef __attribute__((ext_vector_type(4))) float f32x4;

#define BB 4096
#define DD 256
#define KK 512
#define LL 32768
#define QQ 8192

// ---------------- Threefry2x32 (JAX-exact, 20 rounds) ----------------
__host__ __device__ inline void tf2x32(u32 k0, u32 k1, u32 c0, u32 c1, u32& o0, u32& o1) {
  u32 ks2 = k0 ^ k1 ^ 0x1BD11BDAu;
  u32 x0 = c0 + k0, x1 = c1 + k1;
#define TF_R(r) { x0 += x1; x1 = ((x1 << (r)) | (x1 >> (32 - (r)))); x1 ^= x0; }
  TF_R(13) TF_R(15) TF_R(26) TF_R(6)
  x0 += k1; x1 += ks2 + 1u;
  TF_R(17) TF_R(29) TF_R(16) TF_R(24)
  x0 += ks2; x1 += k0 + 2u;
  TF_R(13) TF_R(15) TF_R(26) TF_R(6)
  x0 += k0; x1 += k1 + 3u;
  TF_R(17) TF_R(29) TF_R(16) TF_R(24)
  x0 += k1; x1 += ks2 + 4u;
  TF_R(13) TF_R(15) TF_R(26) TF_R(6)
  x0 += ks2; x1 += k0 + 5u;
#undef TF_R
  o0 = x0; o1 = x1;
}

__device__ inline u32 rbits32(u32 k0, u32 k1, u32 i) {
  u32 a, b;
  tf2x32(k0, k1, 0u, i, a, b);
  return a ^ b;
}

__device__ inline float u01f(u32 bits) {
  return __uint_as_float(0x3f800000u | (bits >> 9)) - 1.0f;
}

__device__ inline float gumbel_at(u32 k0, u32 k1, u32 i) {
  float f = u01f(rbits32(k0, k1, i));
  float u = fmaxf(1e-20f, f + 1e-20f);
  float l1 = (float)log((double)u);
  float l2 = (float)log((double)(-l1));
  return -l2;
}

// XLA f32 ErfInv (Giles polynomial)
__device__ inline float erfinv32(float x) {
  float w = -log1pf(-x * x);
  float p;
  if (w < 5.0f) {
    w -= 2.5f;
    p = 2.81022636e-08f;
    p = fmaf(p, w, 3.43273939e-07f);
    p = fmaf(p, w, -3.5233877e-06f);
    p = fmaf(p, w, -4.39150654e-06f);
    p = fmaf(p, w, 0.00021858087f);
    p = fmaf(p, w, -0.00125372503f);
    p = fmaf(p, w, -0.00417768164f);
    p = fmaf(p, w, 0.246640727f);
    p = fmaf(p, w, 1.50140941f);
  } else {
    w = sqrtf(w) - 3.0f;
    p = -0.000200214257f;
    p = fmaf(p, w, 0.000100950558f);
    p = fmaf(p, w, 0.00134934322f);
    p = fmaf(p, w, -0.00367342844f);
    p = fmaf(p, w, 0.00573950773f);
    p = fmaf(p, w, -0.0076224613f);
    p = fmaf(p, w, 0.00943887047f);
    p = fmaf(p, w, 1.00167406f);
    p = fmaf(p, w, 2.83297682f);
  }
  return p * x;
}

__device__ inline unsigned short f2bf(float f) {
  u32 u = __float_as_uint(f);
  u32 r = (u + 0x7FFFu + ((u >> 16) & 1u)) >> 16;
  return (unsigned short)r;
}

// ---------------- Reductions ----------------
__global__ __launch_bounds__(256)
void k_sumsq(const float* __restrict__ x, int n, float* __restrict__ partial) {
  __shared__ float sm[256];
  float s = 0.0f;
  for (int i = blockIdx.x * 256 + threadIdx.x; i < n; i += gridDim.x * 256) {
    float v = x[i]; s = fmaf(v, v, s);
  }
  sm[threadIdx.x] = s; __syncthreads();
  for (int off = 128; off > 0; off >>= 1) {
    if (threadIdx.x < off) sm[threadIdx.x] += sm[threadIdx.x + off];
    __syncthreads();
  }
  if (threadIdx.x == 0) partial[blockIdx.x] = sm[0];
}

__global__ __launch_bounds__(256)
void k_finalize_rsqrt(const float* __restrict__ partial, float* __restrict__ outv) {
  __shared__ float sm[256];
  int tid = threadIdx.x;
  sm[tid] = partial[tid];
  __syncthreads();
  for (int off = 128; off > 0; off >>= 1) {
    if (tid < off) sm[tid] += sm[tid + off];
    __syncthreads();
  }
  if (tid == 0) {
    float ssum = fmaxf(sm[0], 1e-12f);
    outv[0] = (float)(1.0 / sqrt((double)ssum));
  }
}

// ---------------- f32 GEMMs: 64x64 tile, 4x4 register tile ----------------
__global__ __launch_bounds__(256)
void k_gemm_nt64(const float* __restrict__ A, const float* __restrict__ Bm,
                 float* __restrict__ C, int N) {
  __shared__ float As[16][68], Bs[16][68];
  int tid = threadIdx.x;
  int tx = tid & 15, ty = tid >> 4;
  int rowBase = blockIdx.y * 64, colBase = blockIdx.x * 64;
  float c[4][4] = {};
  for (int kt = 0; kt < 256; kt += 16) {
#pragma unroll
    for (int q = 0; q < 4; q++) {
      int idx = tid + 256 * q;
      int kkx = idx & 15, rr = idx >> 4;
      As[kkx][rr] = A[(size_t)(rowBase + rr) * 256 + kt + kkx];
      Bs[kkx][rr] = Bm[(size_t)(colBase + rr) * 256 + kt + kkx];
    }
    __syncthreads();
#pragma unroll
    for (int kx = 0; kx < 16; kx++) {
      float4 a4 = *(const float4*)&As[kx][ty * 4];
      float4 b4 = *(const float4*)&Bs[kx][tx * 4];
      float av[4] = {a4.x, a4.y, a4.z, a4.w};
      float bv[4] = {b4.x, b4.y, b4.z, b4.w};
#pragma unroll
      for (int r = 0; r < 4; r++)
#pragma unroll
        for (int q = 0; q < 4; q++)
          c[r][q] = fmaf(av[r], bv[q], c[r][q]);
    }
    __syncthreads();
  }
#pragma unroll
  for (int r = 0; r < 4; r++)
#pragma unroll
    for (int q = 0; q < 4; q++)
      C[(size_t)(rowBase + ty * 4 + r) * N + colBase + tx * 4 + q] = c[r][q];
}

// C[M x N] = A[M x K] * Bm[K x N]; grid (N/64, M/64, S)
__global__ __launch_bounds__(256)
void k_gemm_nn64(const float* __restrict__ A, const float* __restrict__ Bm,
                 float* __restrict__ C, int N, int K, int M, int Kc) {
  __shared__ float As[16][68], Bs[16][68];
  int tid = threadIdx.x;
  int tx = tid & 15, ty = tid >> 4;
  int rowBase = blockIdx.y * 64, colBase = blockIdx.x * 64;
  int k0 = blockIdx.z * Kc;
  float c[4][4] = {};
  for (int kt = k0; kt < k0 + Kc; kt += 16) {
#pragma unroll
    for (int q = 0; q < 4; q++) {
      int idx = tid + 256 * q;
      int kkx = idx & 15, rr = idx >> 4;
      As[kkx][rr] = A[(size_t)(rowBase + rr) * K + kt + kkx];
      int kk = (tid >> 6) * 4 + q;
      int jj = tid & 63;
      Bs[kk][jj] = Bm[(size_t)(kt + kk) * N + colBase + jj];
    }
    __syncthreads();
#pragma unroll
    for (int kx = 0; kx < 16; kx++) {
      float4 a4 = *(const float4*)&As[kx][ty * 4];
      float4 b4 = *(const float4*)&Bs[kx][tx * 4];
      float av[4] = {a4.x, a4.y, a4.z, a4.w};
      float bv[4] = {b4.x, b4.y, b4.z, b4.w};
#pragma unroll
      for (int r = 0; r < 4; r++)
#pragma unroll
        for (int q = 0; q < 4; q++)
          c[r][q] = fmaf(av[r], bv[q], c[r][q]);
    }
    __syncthreads();
  }
  float* dst = C + (size_t)blockIdx.z * M * N;
#pragma unroll
  for (int r = 0; r < 4; r++)
#pragma unroll
    for (int q = 0; q < 4; q++)
      dst[(size_t)(rowBase + ty * 4 + r) * N + colBase + tx * 4 + q] = c[r][q];
}

__global__ __launch_bounds__(256)
void k_reduce_div(const float* __restrict__ Cp, int S, int MN,
                  const float* __restrict__ rs, float* __restrict__ out) {
  int i = blockIdx.x * 256 + threadIdx.x;
  if (i >= MN) return;
  float s = 0.0f;
  for (int t = 0; t < S; t++) s += Cp[(size_t)t * MN + i];
  out[i] = s / (rs[i >> 8] + 1e-8f);
}

// ---------------- softmax(y1) + hard argmax(y2), wave-shuffle reductions ----------------
__global__ __launch_bounds__(256)
void k_softmax_assign(const float* __restrict__ knT, float* __restrict__ Y,
                      float* __restrict__ assignOut,
                      u32 g1a, u32 g1b, u32 g2a, u32 g2b) {
  __shared__ float smA[4], smS[4], smM2[4], smS2[4], smV[4];
  __shared__ int smI[4];
  int b = blockIdx.x, tid = threadIdx.x;
  int lane = tid & 63, wid = tid >> 6;
  int i0 = b * KK + tid, i1 = i0 + 256;
  float x0 = knT[i0], x1 = knT[i1];

  float z0 = x0 + gumbel_at(g1a, g1b, (u32)i0);
  float z1 = x1 + gumbel_at(g1a, g1b, (u32)i1);
  float wm = fmaxf(z0, z1);
#pragma unroll
  for (int off = 1; off < 64; off <<= 1) wm = fmaxf(wm, __shfl_xor(wm, off, 64));
  if (lane == 0) smA[wid] = wm;
  __syncthreads();
  float m = fmaxf(fmaxf(smA[0], smA[1]), fmaxf(smA[2], smA[3]));
  float e0 = expf(z0 - m), e1 = expf(z1 - m);
  float ws = e0 + e1;
#pragma unroll
  for (int off = 1; off < 64; off <<= 1) ws += __shfl_xor(ws, off, 64);
  if (lane == 0) smS[wid] = ws;
  __syncthreads();
  float s = (smS[0] + smS[1]) + (smS[2] + smS[3]);
  Y[i0] = e0 / s;
  Y[i1] = e1 / s;

  if (assignOut != nullptr) {
    float w0 = x0 + gumbel_at(g2a, g2b, (u32)i0);
    float w1 = x1 + gumbel_at(g2a, g2b, (u32)i1);
    float wm2 = fmaxf(w0, w1);
#pragma unroll
    for (int off = 1; off < 64; off <<= 1) wm2 = fmaxf(wm2, __shfl_xor(wm2, off, 64));
    if (lane == 0) smM2[wid] = wm2;
    __syncthreads();
    float m2 = fmaxf(fmaxf(smM2[0], smM2[1]), fmaxf(smM2[2], smM2[3]));
    float f0 = expf(w0 - m2), f1 = expf(w1 - m2);
    float ws2 = f0 + f1;
#pragma unroll
    for (int off = 1; off < 64; off <<= 1) ws2 += __shfl_xor(ws2, off, 64);
    if (lane == 0) smS2[wid] = ws2;
    __syncthreads();
    float s2 = (smS2[0] + smS2[1]) + (smS2[2] + smS2[3]);
    float y0 = f0 / s2, y1v = f1 / s2;
    float bv; int bi;
    if (y1v > y0) { bv = y1v; bi = tid + 256; } else { bv = y0; bi = tid; }
#pragma unroll
    for (int off = 1; off < 64; off <<= 1) {
      float ov = __shfl_xor(bv, off, 64);
      int oi = __shfl_xor(bi, off, 64);
      if (ov > bv || (ov == bv && oi < bi)) { bv = ov; bi = oi; }
    }
    if (lane == 0) { smV[wid] = bv; smI[wid] = bi; }
    __syncthreads();
    if (tid == 0) {
      float cv = smV[0]; int ci = smI[0];
#pragma unroll
      for (int t = 1; t < 4; t++) {
        if (smV[t] > cv || (smV[t] == cv && smI[t] < ci)) { cv = smV[t]; ci = smI[t]; }
      }
      assignOut[b] = (float)ci;
    }
  }
}

// ---------------- stochastic binary threshold ----------------
__global__ __launch_bounds__(256)
void k_binary(const float* __restrict__ knT, float* __restrict__ BIN, u32 k3a, u32 k3b) {
  int i = blockIdx.x * 256 + threadIdx.x;
  if (i >= KK * BB) return;
  int k = i / BB, b = i - k * BB;
  float x = knT[b * KK + k];
  float prob = (float)(1.0 / (1.0 + exp(-(double)x)));
  float eps = u01f(rbits32(k3a, k3b, (u32)i));
  BIN[i] = (prob > eps) ? 1.0f : 0.0f;
}

__global__ __launch_bounds__(256)
void k_rowsum(const float* __restrict__ BIN, float* __restrict__ rs) {
  __shared__ float sm[256];
  int k = blockIdx.x, tid = threadIdx.x;
  float s = 0.0f;
  for (int b = tid; b < BB; b += 256) s += BIN[k * BB + b];
  sm[tid] = s; __syncthreads();
  for (int off = 128; off > 0; off >>= 1) {
    if (tid < off) sm[tid] += sm[tid + off];
    __syncthreads();
  }
  if (tid == 0) rs[k] = sm[0];
}

__global__ __launch_bounds__(256)
void k_scale(float* __restrict__ x, const float* __restrict__ fac, int n) {
  int i = blockIdx.x * 256 + threadIdx.x;
  if (i < n) x[i] = x[i] * fac[0];
}

// ---------------- queue = 2*qk + 0.1*normal ----------------
__global__ __launch_bounds__(256)
void k_queue(const float* __restrict__ qk_in, const float* __restrict__ skp,
             float* __restrict__ QUEUE, u32 kqa, u32 kqb) {
  int i = blockIdx.x * 256 + threadIdx.x;
  if (i >= QQ * DD) return;
  float sk = skp[0];
  float qk = qk_in[i] * sk;
  float f = u01f(rbits32(kqa, kqb, (u32)i));
  const float lo = -0.99999994f;
  float u = fmaxf(lo, f * 2.0f + lo);
  float nv = 1.41421354f * erfinv32(u);
  float t = qk + 0.1f * nv;
  QUEUE[i] = t + qk;
}

__global__ __launch_bounds__(256)
void k_rowdot(const float* __restrict__ A, const float* __restrict__ Bv, float* __restrict__ outv) {
  __shared__ float sm[256];
  int r = blockIdx.x, tid = threadIdx.x;
  sm[tid] = A[r * 256 + tid] * Bv[r * 256 + tid];
  __syncthreads();
  for (int off = 128; off > 0; off >>= 1) {
    if (tid < off) sm[tid] += sm[tid + off];
    __syncthreads();
  }
  if (tid == 0) outv[r] = sm[0];
}

// ---------------- f32 -> bf16 conversion ----------------
__global__ __launch_bounds__(256)
void k_cvt_bf16(const float* __restrict__ src, unsigned short* __restrict__ dst, int n) {
  int i = (blockIdx.x * 256 + threadIdx.x) * 4;
  if (i >= n) return;
  float4 v = *(const float4*)(src + i);
  ushort2 a, b;
  a.x = f2bf(v.x); a.y = f2bf(v.y);
  b.x = f2bf(v.z); b.y = f2bf(v.w);
  *(ushort2*)(dst + i) = a;
  *(ushort2*)(dst + i + 2) = b;
}

// ---------------- fused bf16-MFMA GEMM + sum-exp (fixed m=0) ----------------
// |logits| < 0.01 (globally-l2-normalized operands) -> sum-exp needs no max.
// 1-D grid nblk = nxblk*nsplit, decoded so all x-blocks of a column-slice share
// lin%8 (same XCD under round-robin dispatch -> B slice stays XCD-L2-resident).
// Block = 4 waves x 32 rows = 128 rows. A (2 tilesets = 64 VGPR) stays in regs.
// ps layout: [nsplit][M].
__global__ __launch_bounds__(256, 4)
void k_lse_mfma3(const unsigned short* __restrict__ Qb, const unsigned short* __restrict__ Nb,
                 const float* __restrict__ scale_ptr, int Lper, int M, int nxblk,
                 float* __restrict__ ps) {
  int lin = blockIdx.x;
  int xb = (lin >> 3) % nxblk;
  int yb = (lin & 7) + 8 * (lin / (8 * nxblk));
  int tid = threadIdx.x;
  int wave = tid >> 6, lane = tid & 63;
  int rowBase = xb * 128 + wave * 32;
  int j0 = yb * Lper;
  float lsc = scale_ptr[0] / 0.07f;
  int lr = lane & 15;
  int lk = (lane >> 4) * 8;

  short8 afr[2][8];
#pragma unroll
  for (int ts = 0; ts < 2; ts++)
#pragma unroll
    for (int kf = 0; kf < 8; kf++)
      afr[ts][kf] = *(const short8*)(Qb + (size_t)(rowBase + ts * 16 + lr) * 256 + kf * 32 + lk);

  float s[2][4];
#pragma unroll
  for (int ts = 0; ts < 2; ts++)
#pragma unroll
    for (int r = 0; r < 4; r++) s[ts][r] = 0.0f;

  for (int j = 0; j < Lper; j += 16) {
    const unsigned short* bbase = Nb + (size_t)(j0 + j + lr) * 256 + lk;
    short8 bfr[8];
#pragma unroll
    for (int kf = 0; kf < 8; kf++) bfr[kf] = *(const short8*)(bbase + kf * 32);
#pragma unroll
    for (int ts = 0; ts < 2; ts++) {
      f32x4 acc = {0.f, 0.f, 0.f, 0.f};
#pragma unroll
      for (int kf = 0; kf < 8; kf++)
        acc = __builtin_amdgcn_mfma_f32_16x16x32_bf16(afr[ts][kf], bfr[kf], acc, 0, 0, 0);
#pragma unroll
      for (int r = 0; r < 4; r++)
        s[ts][r] += __expf(acc[r] * lsc);
    }
  }
#pragma unroll
  for (int off = 1; off < 16; off <<= 1)
#pragma unroll
    for (int ts = 0; ts < 2; ts++)
#pragma unroll
      for (int r = 0; r < 4; r++)
        s[ts][r] += __shfl_xor(s[ts][r], off, 64);
  if (lr == 0) {
    int rg = (lane >> 4) * 4;
#pragma unroll
    for (int ts = 0; ts < 2; ts++)
#pragma unroll
      for (int r = 0; r < 4; r++)
        ps[(size_t)yb * M + rowBase + ts * 16 + rg + r] = s[ts][r];
  }
}

// partial row-LSE sums: grid nb blocks, one row per thread (M = nb*256)
__global__ __launch_bounds__(256)
void k_lse_partial(const float* __restrict__ ps, int nsplit,
                   const float* __restrict__ lpos, int M, float* __restrict__ partial) {
  __shared__ float sm[256];
  int tid = threadIdx.x;
  int row = blockIdx.x * 256 + tid;
  float s = 0.0f;
  for (int t = 0; t < nsplit; t++) s += ps[(size_t)t * M + row];
  float z0 = lpos[row] / 0.07f;
  s += expf(z0);
  float acc = logf(s) - z0;
  sm[tid] = acc; __syncthreads();
  for (int off = 128; off > 0; off >>= 1) {
    if (tid < off) sm[tid] += sm[tid + off];
    __syncthreads();
  }
  if (tid == 0) partial[blockIdx.x] = sm[0];
}

__global__ void k_loss_merge(const float* __restrict__ PN, int nN, int MN,
                             const float* __restrict__ PK, int nK, int MK,
                             float* __restrict__ outLoss) {
  if (threadIdx.x == 0) {
    float a = 0.0f, b = 0.0f;
    for (int i = 0; i < nN; i++) a += PN[i];
    for (int i = 0; i < nK; i++) b += PK[i];
    outLoss[0] = a / (float)MN + b / (float)MK;
  }
}

// ---------------- launch ----------------
extern "C" void kernel_launch(void* const* d_in, const int* in_sizes, int n_in,
                              void* d_out, int out_size, void* d_ws, size_t ws_size,
                              hipStream_t stream) {
  const float* feat[2] = {(const float*)d_in[0], (const float*)d_in[1]};
  const float* ctx[2]  = {(const float*)d_in[2], (const float*)d_in[3]};
  const float* queue_n = (const float*)d_in[4];
  const float* queue_k = (const float*)d_in[5];

  float* W = (float*)d_ws;
  size_t o = 0;
  float* T     = W + o; o += (size_t)BB * KK;
  float* Yb    = W + o; o += (size_t)BB * KK;   // also split-K partials (CP)
  float* BIN   = W + o; o += (size_t)KK * BB;
  float* AGGN1 = W + o; o += (size_t)BB * DD;
  float* AGGK1 = W + o; o += (size_t)KK * DD;
  float* QUEUE = W + o; o += (size_t)QQ * DD;
  float* RS    = W + o; o += KK;
  float* PART  = W + o; o += 256;
  float* SCAL  = W + o; o += 8;
  float* LPOSN = W + o; o += BB;
  float* LPOSK = W + o; o += KK;
  float* PNp   = W + o; o += 32;
  float* PKp   = W + o; o += 32;

  // bf16 loss operands overlay the dead T/Yb/BIN region
  unsigned short* QNb  = (unsigned short*)T;                 // 32768*256
  unsigned short* QUb  = QNb + (size_t)LL * DD;              // 8192*256
  unsigned short* AGNb = QUb + (size_t)QQ * DD;              // 4096*256
  unsigned short* AGKb = AGNb + (size_t)BB * DD;             // 512*256
  // PSBUF lives in the leftover tail of BIN (1.75 MB free; max need 1.0 MB)
  float* PSBUF = (float*)(AGKb + (size_t)KK * DD);
  float* CP = Yb;                                            // split-K partials

  float* out = (float*)d_out;
  float* outAssign = out;
  float* outAggn2  = out + BB;
  float* outAggk2  = out + BB + (size_t)BB * DD;
  float* outLoss   = out + BB + (size_t)BB * DD + (size_t)KK * DD;

  u32 kq0, kq1, kc[2][2];
  tf2x32(0u, 42u, 0u, 0u, kq0, kq1);
  tf2x32(0u, 42u, 0u, 1u, kc[0][0], kc[0][1]);
  tf2x32(0u, 42u, 0u, 2u, kc[1][0], kc[1][1]);
  u32 sub[2][3][2];
  for (int br = 0; br < 2; br++)
    for (int t = 0; t < 3; t++)
      tf2x32(kc[br][0], kc[br][1], 0u, (u32)t, sub[br][t][0], sub[br][t][1]);

  k_sumsq<<<256, 256, 0, stream>>>(queue_n, LL * DD, PART);
  k_finalize_rsqrt<<<1, 256, 0, stream>>>(PART, SCAL + 0);   // sn
  k_sumsq<<<256, 256, 0, stream>>>(queue_k, QQ * DD, PART);
  k_finalize_rsqrt<<<1, 256, 0, stream>>>(PART, SCAL + 1);   // sk

  for (int br = 0; br < 2; br++) {
    float* aggn = (br == 0) ? AGGN1 : outAggn2;
    float* aggk = (br == 0) ? AGGK1 : outAggk2;
    k_gemm_nt64<<<dim3(KK / 64, BB / 64), 256, 0, stream>>>(feat[br], ctx[br], T, KK);
    k_softmax_assign<<<BB, 256, 0, stream>>>(T, Yb, br == 0 ? outAssign : nullptr,
        sub[br][0][0], sub[br][0][1], sub[br][1][0], sub[br][1][1]);
    k_binary<<<(KK * BB) / 256, 256, 0, stream>>>(T, BIN, sub[br][2][0], sub[br][2][1]);
    k_rowsum<<<KK, 256, 0, stream>>>(BIN, RS);
    k_gemm_nn64<<<dim3(DD / 64, BB / 64, 1), 256, 0, stream>>>(Yb, ctx[br], aggn, DD, KK, BB, KK);
    k_gemm_nn64<<<dim3(DD / 64, KK / 64, 8), 256, 0, stream>>>(BIN, feat[br], CP, DD, BB, KK, 512);
    k_reduce_div<<<(KK * DD) / 256, 256, 0, stream>>>(CP, 8, KK * DD, RS, aggk);
    k_sumsq<<<256, 256, 0, stream>>>(aggn, BB * DD, PART);
    k_finalize_rsqrt<<<1, 256, 0, stream>>>(PART, SCAL + 3);
    k_scale<<<(BB * DD) / 256, 256, 0, stream>>>(aggn, SCAL + 3, BB * DD);
    k_sumsq<<<256, 256, 0, stream>>>(aggk, KK * DD, PART);
    k_finalize_rsqrt<<<1, 256, 0, stream>>>(PART, SCAL + 4);
    k_scale<<<(KK * DD) / 256, 256, 0, stream>>>(aggk, SCAL + 4, KK * DD);
  }

  k_queue<<<(QQ * DD) / 256, 256, 0, stream>>>(queue_k, SCAL + 1, QUEUE, kq0, kq1);
  k_sumsq<<<256, 256, 0, stream>>>(QUEUE, QQ * DD, PART);
  k_finalize_rsqrt<<<1, 256, 0, stream>>>(PART, SCAL + 2);   // fq

  // positives (f32)
  k_rowdot<<<BB, 256, 0, stream>>>(AGGN1, outAggn2, LPOSN);
  k_rowdot<<<KK, 256, 0, stream>>>(AGGK1, outAggk2, LPOSK);

  // bf16 conversions (T/Yb/BIN dead from here)
  k_cvt_bf16<<<(LL * DD) / 1024, 256, 0, stream>>>(queue_n, QNb, LL * DD);
  k_cvt_bf16<<<(QQ * DD) / 1024, 256, 0, stream>>>(QUEUE, QUb, QQ * DD);
  k_cvt_bf16<<<(BB * DD) / 1024, 256, 0, stream>>>(AGGN1, AGNb, BB * DD);
  k_cvt_bf16<<<(KK * DD) / 1024, 256, 0, stream>>>(AGGK1, AGKb, KK * DD);

  // loss_n: q = agg_n_1, negs = queue_n (sn folded). nxblk=32, nsplit=64 -> 2048 blocks.
  k_lse_mfma3<<<32 * 64, 256, 0, stream>>>(AGNb, QNb, SCAL + 0, LL / 64, BB, BB / 128, PSBUF);
  k_lse_partial<<<BB / 256, 256, 0, stream>>>(PSBUF, 64, LPOSN, BB, PNp);
  // loss_k: q = agg_k_1, negs = QUEUE (fq folded). nxblk=4, nsplit=256 -> 1024 blocks.
  k_lse_mfma3<<<4 * 256, 256, 0, stream>>>(AGKb, QUb, SCAL + 2, QQ / 256, KK, KK / 128, PSBUF);
  k_lse_partial<<<KK / 256, 256, 0, stream>>>(PSBUF, 256, LPOSK, KK, PKp);
  k_loss_merge<<<1, 64, 0, stream>>>(PNp, BB / 256, BB, PKp, KK / 256, KK, outLoss);
}

// Round 6
// 675.526 us; speedup vs baseline: 1.0686x; 1.0686x over previous
//
#include <hip/hip_runtime.h>
#include <stdint.h>
#include <math.h>

typedef unsigned int u32;
typedef __attribute__((ext_vector_type(8))) short short8;
typedef __attribute__((ext_vector_type(4))) float f32x4;

#define BB 4096
#define DD 256
#define KK 512
#define LL 32768
#define QQ 8192

// ---------------- Threefry2x32 (JAX-exact, 20 rounds) ----------------
__host__ __device__ inline void tf2x32(u32 k0, u32 k1, u32 c0, u32 c1, u32& o0, u32& o1) {
  u32 ks2 = k0 ^ k1 ^ 0x1BD11BDAu;
  u32 x0 = c0 + k0, x1 = c1 + k1;
#define TF_R(r) { x0 += x1; x1 = ((x1 << (r)) | (x1 >> (32 - (r)))); x1 ^= x0; }
  TF_R(13) TF_R(15) TF_R(26) TF_R(6)
  x0 += k1; x1 += ks2 + 1u;
  TF_R(17) TF_R(29) TF_R(16) TF_R(24)
  x0 += ks2; x1 += k0 + 2u;
  TF_R(13) TF_R(15) TF_R(26) TF_R(6)
  x0 += k0; x1 += k1 + 3u;
  TF_R(17) TF_R(29) TF_R(16) TF_R(24)
  x0 += k1; x1 += ks2 + 4u;
  TF_R(13) TF_R(15) TF_R(26) TF_R(6)
  x0 += ks2; x1 += k0 + 5u;
#undef TF_R
  o0 = x0; o1 = x1;
}

__device__ inline u32 rbits32(u32 k0, u32 k1, u32 i) {
  u32 a, b;
  tf2x32(k0, k1, 0u, i, a, b);
  return a ^ b;
}

__device__ inline float u01f(u32 bits) {
  return __uint_as_float(0x3f800000u | (bits >> 9)) - 1.0f;
}

// f64-log gumbel: argmax-critical path only (bit-stable vs CPU libm)
__device__ inline float gumbel_at(u32 k0, u32 k1, u32 i) {
  float f = u01f(rbits32(k0, k1, i));
  float u = fmaxf(1e-20f, f + 1e-20f);
  float l1 = (float)log((double)u);
  float l2 = (float)log((double)(-l1));
  return -l2;
}

// fast f32 gumbel: continuous-output paths (y1 softmax) — ~1ulp logs
__device__ inline float gumbel_f32(u32 k0, u32 k1, u32 i) {
  float f = u01f(rbits32(k0, k1, i));
  float u = fmaxf(1e-20f, f + 1e-20f);
  float l1 = __logf(u);
  return -__logf(-l1);
}

// XLA f32 ErfInv (Giles polynomial)
__device__ inline float erfinv32(float x) {
  float w = -log1pf(-x * x);
  float p;
  if (w < 5.0f) {
    w -= 2.5f;
    p = 2.81022636e-08f;
    p = fmaf(p, w, 3.43273939e-07f);
    p = fmaf(p, w, -3.5233877e-06f);
    p = fmaf(p, w, -4.39150654e-06f);
    p = fmaf(p, w, 0.00021858087f);
    p = fmaf(p, w, -0.00125372503f);
    p = fmaf(p, w, -0.00417768164f);
    p = fmaf(p, w, 0.246640727f);
    p = fmaf(p, w, 1.50140941f);
  } else {
    w = sqrtf(w) - 3.0f;
    p = -0.000200214257f;
    p = fmaf(p, w, 0.000100950558f);
    p = fmaf(p, w, 0.00134934322f);
    p = fmaf(p, w, -0.00367342844f);
    p = fmaf(p, w, 0.00573950773f);
    p = fmaf(p, w, -0.0076224613f);
    p = fmaf(p, w, 0.00943887047f);
    p = fmaf(p, w, 1.00167406f);
    p = fmaf(p, w, 2.83297682f);
  }
  return p * x;
}

__device__ inline unsigned short f2bf(float f) {
  u32 u = __float_as_uint(f);
  u32 r = (u + 0x7FFFu + ((u >> 16) & 1u)) >> 16;
  return (unsigned short)r;
}

// ---------------- Reductions ----------------
__global__ __launch_bounds__(256)
void k_sumsq(const float* __restrict__ x, int n, float* __restrict__ partial) {
  __shared__ float sm[256];
  float s = 0.0f;
  for (int i = blockIdx.x * 256 + threadIdx.x; i < n; i += gridDim.x * 256) {
    float v = x[i]; s = fmaf(v, v, s);
  }
  sm[threadIdx.x] = s; __syncthreads();
  for (int off = 128; off > 0; off >>= 1) {
    if (threadIdx.x < off) sm[threadIdx.x] += sm[threadIdx.x + off];
    __syncthreads();
  }
  if (threadIdx.x == 0) partial[blockIdx.x] = sm[0];
}

__global__ __launch_bounds__(256)
void k_finalize_rsqrt(const float* __restrict__ partial, float* __restrict__ outv) {
  __shared__ float sm[256];
  int tid = threadIdx.x;
  sm[tid] = partial[tid];
  __syncthreads();
  for (int off = 128; off > 0; off >>= 1) {
    if (tid < off) sm[tid] += sm[tid + off];
    __syncthreads();
  }
  if (tid == 0) {
    float ssum = fmaxf(sm[0], 1e-12f);
    outv[0] = (float)(1.0 / sqrt((double)ssum));
  }
}

// ---------------- f32 GEMMs: 64x64 tile, 4x4 register tile ----------------
__global__ __launch_bounds__(256)
void k_gemm_nt64(const float* __restrict__ A, const float* __restrict__ Bm,
                 float* __restrict__ C, int N) {
  __shared__ float As[16][68], Bs[16][68];
  int tid = threadIdx.x;
  int tx = tid & 15, ty = tid >> 4;
  int rowBase = blockIdx.y * 64, colBase = blockIdx.x * 64;
  float c[4][4] = {};
  for (int kt = 0; kt < 256; kt += 16) {
#pragma unroll
    for (int q = 0; q < 4; q++) {
      int idx = tid + 256 * q;
      int kkx = idx & 15, rr = idx >> 4;
      As[kkx][rr] = A[(size_t)(rowBase + rr) * 256 + kt + kkx];
      Bs[kkx][rr] = Bm[(size_t)(colBase + rr) * 256 + kt + kkx];
    }
    __syncthreads();
#pragma unroll
    for (int kx = 0; kx < 16; kx++) {
      float4 a4 = *(const float4*)&As[kx][ty * 4];
      float4 b4 = *(const float4*)&Bs[kx][tx * 4];
      float av[4] = {a4.x, a4.y, a4.z, a4.w};
      float bv[4] = {b4.x, b4.y, b4.z, b4.w};
#pragma unroll
      for (int r = 0; r < 4; r++)
#pragma unroll
        for (int q = 0; q < 4; q++)
          c[r][q] = fmaf(av[r], bv[q], c[r][q]);
    }
    __syncthreads();
  }
#pragma unroll
  for (int r = 0; r < 4; r++)
#pragma unroll
    for (int q = 0; q < 4; q++)
      C[(size_t)(rowBase + ty * 4 + r) * N + colBase + tx * 4 + q] = c[r][q];
}

// C[M x N] = A[M x K] * Bm[K x N]; grid (N/64, M/64, S)
__global__ __launch_bounds__(256)
void k_gemm_nn64(const float* __restrict__ A, const float* __restrict__ Bm,
                 float* __restrict__ C, int N, int K, int M, int Kc) {
  __shared__ float As[16][68], Bs[16][68];
  int tid = threadIdx.x;
  int tx = tid & 15, ty = tid >> 4;
  int rowBase = blockIdx.y * 64, colBase = blockIdx.x * 64;
  int k0 = blockIdx.z * Kc;
  float c[4][4] = {};
  for (int kt = k0; kt < k0 + Kc; kt += 16) {
#pragma unroll
    for (int q = 0; q < 4; q++) {
      int idx = tid + 256 * q;
      int kkx = idx & 15, rr = idx >> 4;
      As[kkx][rr] = A[(size_t)(rowBase + rr) * K + kt + kkx];
      int kk = (tid >> 6) * 4 + q;
      int jj = tid & 63;
      Bs[kk][jj] = Bm[(size_t)(kt + kk) * N + colBase + jj];
    }
    __syncthreads();
#pragma unroll
    for (int kx = 0; kx < 16; kx++) {
      float4 a4 = *(const float4*)&As[kx][ty * 4];
      float4 b4 = *(const float4*)&Bs[kx][tx * 4];
      float av[4] = {a4.x, a4.y, a4.z, a4.w};
      float bv[4] = {b4.x, b4.y, b4.z, b4.w};
#pragma unroll
      for (int r = 0; r < 4; r++)
#pragma unroll
        for (int q = 0; q < 4; q++)
          c[r][q] = fmaf(av[r], bv[q], c[r][q]);
    }
    __syncthreads();
  }
  float* dst = C + (size_t)blockIdx.z * M * N;
#pragma unroll
  for (int r = 0; r < 4; r++)
#pragma unroll
    for (int q = 0; q < 4; q++)
      dst[(size_t)(rowBase + ty * 4 + r) * N + colBase + tx * 4 + q] = c[r][q];
}

__global__ __launch_bounds__(256)
void k_reduce_div(const float* __restrict__ Cp, int S, int MN,
                  const float* __restrict__ rs, float* __restrict__ out) {
  int i = blockIdx.x * 256 + threadIdx.x;
  if (i >= MN) return;
  float s = 0.0f;
  for (int t = 0; t < S; t++) s += Cp[(size_t)t * MN + i];
  out[i] = s / (rs[i >> 8] + 1e-8f);
}

// ---------------- softmax(y1) + hard argmax(y2), wave-shuffle reductions ----------------
__global__ __launch_bounds__(256)
void k_softmax_assign(const float* __restrict__ knT, float* __restrict__ Y,
                      float* __restrict__ assignOut,
                      u32 g1a, u32 g1b, u32 g2a, u32 g2b) {
  __shared__ float smA[4], smS[4], smM2[4], smS2[4], smV[4];
  __shared__ int smI[4];
  int b = blockIdx.x, tid = threadIdx.x;
  int lane = tid & 63, wid = tid >> 6;
  int i0 = b * KK + tid, i1 = i0 + 256;
  float x0 = knT[i0], x1 = knT[i1];

  // y1 path: fast f32 gumbels (feeds only continuous outputs)
  float z0 = x0 + gumbel_f32(g1a, g1b, (u32)i0);
  float z1 = x1 + gumbel_f32(g1a, g1b, (u32)i1);
  float wm = fmaxf(z0, z1);
#pragma unroll
  for (int off = 1; off < 64; off <<= 1) wm = fmaxf(wm, __shfl_xor(wm, off, 64));
  if (lane == 0) smA[wid] = wm;
  __syncthreads();
  float m = fmaxf(fmaxf(smA[0], smA[1]), fmaxf(smA[2], smA[3]));
  float e0 = expf(z0 - m), e1 = expf(z1 - m);
  float ws = e0 + e1;
#pragma unroll
  for (int off = 1; off < 64; off <<= 1) ws += __shfl_xor(ws, off, 64);
  if (lane == 0) smS[wid] = ws;
  __syncthreads();
  float s = (smS[0] + smS[1]) + (smS[2] + smS[3]);
  Y[i0] = e0 / s;
  Y[i1] = e1 / s;

  if (assignOut != nullptr) {
    // argmax path: keep f64-log gumbels (bit-stable, no discrete re-roll)
    float w0 = x0 + gumbel_at(g2a, g2b, (u32)i0);
    float w1 = x1 + gumbel_at(g2a, g2b, (u32)i1);
    float wm2 = fmaxf(w0, w1);
#pragma unroll
    for (int off = 1; off < 64; off <<= 1) wm2 = fmaxf(wm2, __shfl_xor(wm2, off, 64));
    if (lane == 0) smM2[wid] = wm2;
    __syncthreads();
    float m2 = fmaxf(fmaxf(smM2[0], smM2[1]), fmaxf(smM2[2], smM2[3]));
    float f0 = expf(w0 - m2), f1 = expf(w1 - m2);
    float ws2 = f0 + f1;
#pragma unroll
    for (int off = 1; off < 64; off <<= 1) ws2 += __shfl_xor(ws2, off, 64);
    if (lane == 0) smS2[wid] = ws2;
    __syncthreads();
    float s2 = (smS2[0] + smS2[1]) + (smS2[2] + smS2[3]);
    float y0 = f0 / s2, y1v = f1 / s2;
    float bv; int bi;
    if (y1v > y0) { bv = y1v; bi = tid + 256; } else { bv = y0; bi = tid; }
#pragma unroll
    for (int off = 1; off < 64; off <<= 1) {
      float ov = __shfl_xor(bv, off, 64);
      int oi = __shfl_xor(bi, off, 64);
      if (ov > bv || (ov == bv && oi < bi)) { bv = ov; bi = oi; }
    }
    if (lane == 0) { smV[wid] = bv; smI[wid] = bi; }
    __syncthreads();
    if (tid == 0) {
      float cv = smV[0]; int ci = smI[0];
#pragma unroll
      for (int t = 1; t < 4; t++) {
        if (smV[t] > cv || (smV[t] == cv && smI[t] < ci)) { cv = smV[t]; ci = smI[t]; }
      }
      assignOut[b] = (float)ci;
    }
  }
}

// ---------------- stochastic binary threshold ----------------
__global__ __launch_bounds__(256)
void k_binary(const float* __restrict__ knT, float* __restrict__ BIN, u32 k3a, u32 k3b) {
  int i = blockIdx.x * 256 + threadIdx.x;
  if (i >= KK * BB) return;
  int k = i / BB, b = i - k * BB;
  float x = knT[b * KK + k];
  float prob = (float)(1.0 / (1.0 + exp(-(double)x)));
  float eps = u01f(rbits32(k3a, k3b, (u32)i));
  BIN[i] = (prob > eps) ? 1.0f : 0.0f;
}

__global__ __launch_bounds__(256)
void k_rowsum(const float* __restrict__ BIN, float* __restrict__ rs) {
  __shared__ float sm[256];
  int k = blockIdx.x, tid = threadIdx.x;
  float s = 0.0f;
  for (int b = tid; b < BB; b += 256) s += BIN[k * BB + b];
  sm[tid] = s; __syncthreads();
  for (int off = 128; off > 0; off >>= 1) {
    if (tid < off) sm[tid] += sm[tid + off];
    __syncthreads();
  }
  if (tid == 0) rs[k] = sm[0];
}

__global__ __launch_bounds__(256)
void k_scale(float* __restrict__ x, const float* __restrict__ fac, int n) {
  int i = blockIdx.x * 256 + threadIdx.x;
  if (i < n) x[i] = x[i] * fac[0];
}

// ---------------- queue = 2*qk + 0.1*normal ----------------
__global__ __launch_bounds__(256)
void k_queue(const float* __restrict__ qk_in, const float* __restrict__ skp,
             float* __restrict__ QUEUE, u32 kqa, u32 kqb) {
  int i = blockIdx.x * 256 + threadIdx.x;
  if (i >= QQ * DD) return;
  float sk = skp[0];
  float qk = qk_in[i] * sk;
  float f = u01f(rbits32(kqa, kqb, (u32)i));
  const float lo = -0.99999994f;
  float u = fmaxf(lo, f * 2.0f + lo);
  float nv = 1.41421354f * erfinv32(u);
  float t = qk + 0.1f * nv;
  QUEUE[i] = t + qk;
}

__global__ __launch_bounds__(256)
void k_rowdot(const float* __restrict__ A, const float* __restrict__ Bv, float* __restrict__ outv) {
  __shared__ float sm[256];
  int r = blockIdx.x, tid = threadIdx.x;
  sm[tid] = A[r * 256 + tid] * Bv[r * 256 + tid];
  __syncthreads();
  for (int off = 128; off > 0; off >>= 1) {
    if (tid < off) sm[tid] += sm[tid + off];
    __syncthreads();
  }
  if (tid == 0) outv[r] = sm[0];
}

// ---------------- f32 -> bf16 conversion ----------------
__global__ __launch_bounds__(256)
void k_cvt_bf16(const float* __restrict__ src, unsigned short* __restrict__ dst, int n) {
  int i = (blockIdx.x * 256 + threadIdx.x) * 4;
  if (i >= n) return;
  float4 v = *(const float4*)(src + i);
  ushort2 a, b;
  a.x = f2bf(v.x); a.y = f2bf(v.y);
  b.x = f2bf(v.z); b.y = f2bf(v.w);
  *(ushort2*)(dst + i) = a;
  *(ushort2*)(dst + i + 2) = b;
}

// ---------------- fused bf16-MFMA GEMM + sum-exp (fixed m=0) ----------------
// |logits| < 0.01 (globally-l2-normalized operands) -> sum-exp needs no max.
// Block = 4 waves x 32 rows = 128 rows. waves_per_eu(4,4): VGPR budget 128 so
// the scheduler does NOT squeeze to 64 for 8 waves (R5: VGPR=52, A rematerialized
// in-loop -> latency-bound). afr pinned via asm to forbid load sinking.
__global__ __launch_bounds__(256) __attribute__((amdgpu_waves_per_eu(4, 4)))
void k_lse_mfma3(const unsigned short* __restrict__ Qb, const unsigned short* __restrict__ Nb,
                 const float* __restrict__ scale_ptr, int Lper, int M, int nxblk,
                 float* __restrict__ ps) {
  int lin = blockIdx.x;
  int xb = (lin >> 3) % nxblk;
  int yb = (lin & 7) + 8 * (lin / (8 * nxblk));
  int tid = threadIdx.x;
  int wave = tid >> 6, lane = tid & 63;
  int rowBase = xb * 128 + wave * 32;
  int j0 = yb * Lper;
  float lsc = scale_ptr[0] / 0.07f;
  int lr = lane & 15;
  int lk = (lane >> 4) * 8;

  short8 afr[2][8];
#pragma unroll
  for (int ts = 0; ts < 2; ts++)
#pragma unroll
    for (int kf = 0; kf < 8; kf++)
      afr[ts][kf] = *(const short8*)(Qb + (size_t)(rowBase + ts * 16 + lr) * 256 + kf * 32 + lk);
  // pin A fragments in VGPRs: asm redefines them, loads can't be re-sunk
#pragma unroll
  for (int ts = 0; ts < 2; ts++)
#pragma unroll
    for (int kf = 0; kf < 8; kf++)
      asm volatile("" : "+v"(afr[ts][kf]));

  float s[2][4];
#pragma unroll
  for (int ts = 0; ts < 2; ts++)
#pragma unroll
    for (int r = 0; r < 4; r++) s[ts][r] = 0.0f;

  for (int j = 0; j < Lper; j += 16) {
    const unsigned short* bbase = Nb + (size_t)(j0 + j + lr) * 256 + lk;
    short8 bfr[8];
#pragma unroll
    for (int kf = 0; kf < 8; kf++) bfr[kf] = *(const short8*)(bbase + kf * 32);
#pragma unroll
    for (int ts = 0; ts < 2; ts++) {
      f32x4 acc = {0.f, 0.f, 0.f, 0.f};
#pragma unroll
      for (int kf = 0; kf < 8; kf++)
        acc = __builtin_amdgcn_mfma_f32_16x16x32_bf16(afr[ts][kf], bfr[kf], acc, 0, 0, 0);
#pragma unroll
      for (int r = 0; r < 4; r++)
        s[ts][r] += __expf(acc[r] * lsc);
    }
  }
#pragma unroll
  for (int off = 1; off < 16; off <<= 1)
#pragma unroll
    for (int ts = 0; ts < 2; ts++)
#pragma unroll
      for (int r = 0; r < 4; r++)
        s[ts][r] += __shfl_xor(s[ts][r], off, 64);
  if (lr == 0) {
    int rg = (lane >> 4) * 4;
#pragma unroll
    for (int ts = 0; ts < 2; ts++)
#pragma unroll
      for (int r = 0; r < 4; r++)
        ps[(size_t)yb * M + rowBase + ts * 16 + rg + r] = s[ts][r];
  }
}

// partial row-LSE sums: grid nb blocks, one row per thread (M = nb*256)
__global__ __launch_bounds__(256)
void k_lse_partial(const float* __restrict__ ps, int nsplit,
                   const float* __restrict__ lpos, int M, float* __restrict__ partial) {
  __shared__ float sm[256];
  int tid = threadIdx.x;
  int row = blockIdx.x * 256 + tid;
  float s = 0.0f;
  for (int t = 0; t < nsplit; t++) s += ps[(size_t)t * M + row];
  float z0 = lpos[row] / 0.07f;
  s += expf(z0);
  float acc = logf(s) - z0;
  sm[tid] = acc; __syncthreads();
  for (int off = 128; off > 0; off >>= 1) {
    if (tid < off) sm[tid] += sm[tid + off];
    __syncthreads();
  }
  if (tid == 0) partial[blockIdx.x] = sm[0];
}

__global__ void k_loss_merge(const float* __restrict__ PN, int nN, int MN,
                             const float* __restrict__ PK, int nK, int MK,
                             float* __restrict__ outLoss) {
  if (threadIdx.x == 0) {
    float a = 0.0f, b = 0.0f;
    for (int i = 0; i < nN; i++) a += PN[i];
    for (int i = 0; i < nK; i++) b += PK[i];
    outLoss[0] = a / (float)MN + b / (float)MK;
  }
}

// ---------------- launch ----------------
extern "C" void kernel_launch(void* const* d_in, const int* in_sizes, int n_in,
                              void* d_out, int out_size, void* d_ws, size_t ws_size,
                              hipStream_t stream) {
  const float* feat[2] = {(const float*)d_in[0], (const float*)d_in[1]};
  const float* ctx[2]  = {(const float*)d_in[2], (const float*)d_in[3]};
  const float* queue_n = (const float*)d_in[4];
  const float* queue_k = (const float*)d_in[5];

  float* W = (float*)d_ws;
  size_t o = 0;
  float* T     = W + o; o += (size_t)BB * KK;
  float* Yb    = W + o; o += (size_t)BB * KK;   // also split-K partials (CP)
  float* BIN   = W + o; o += (size_t)KK * BB;
  float* AGGN1 = W + o; o += (size_t)BB * DD;
  float* AGGK1 = W + o; o += (size_t)KK * DD;
  float* QUEUE = W + o; o += (size_t)QQ * DD;
  float* RS    = W + o; o += KK;
  float* PART  = W + o; o += 256;
  float* SCAL  = W + o; o += 8;
  float* LPOSN = W + o; o += BB;
  float* LPOSK = W + o; o += KK;
  float* PNp   = W + o; o += 32;
  float* PKp   = W + o; o += 32;

  // bf16 loss operands overlay the dead T/Yb/BIN region
  unsigned short* QNb  = (unsigned short*)T;                 // 32768*256
  unsigned short* QUb  = QNb + (size_t)LL * DD;              // 8192*256
  unsigned short* AGNb = QUb + (size_t)QQ * DD;              // 4096*256
  unsigned short* AGKb = AGNb + (size_t)BB * DD;             // 512*256
  float* PSBUF = (float*)(AGKb + (size_t)KK * DD);
  float* CP = Yb;                                            // split-K partials

  float* out = (float*)d_out;
  float* outAssign = out;
  float* outAggn2  = out + BB;
  float* outAggk2  = out + BB + (size_t)BB * DD;
  float* outLoss   = out + BB + (size_t)BB * DD + (size_t)KK * DD;

  u32 kq0, kq1, kc[2][2];
  tf2x32(0u, 42u, 0u, 0u, kq0, kq1);
  tf2x32(0u, 42u, 0u, 1u, kc[0][0], kc[0][1]);
  tf2x32(0u, 42u, 0u, 2u, kc[1][0], kc[1][1]);
  u32 sub[2][3][2];
  for (int br = 0; br < 2; br++)
    for (int t = 0; t < 3; t++)
      tf2x32(kc[br][0], kc[br][1], 0u, (u32)t, sub[br][t][0], sub[br][t][1]);

  k_sumsq<<<256, 256, 0, stream>>>(queue_n, LL * DD, PART);
  k_finalize_rsqrt<<<1, 256, 0, stream>>>(PART, SCAL + 0);   // sn
  k_sumsq<<<256, 256, 0, stream>>>(queue_k, QQ * DD, PART);
  k_finalize_rsqrt<<<1, 256, 0, stream>>>(PART, SCAL + 1);   // sk

  for (int br = 0; br < 2; br++) {
    float* aggn = (br == 0) ? AGGN1 : outAggn2;
    float* aggk = (br == 0) ? AGGK1 : outAggk2;
    k_gemm_nt64<<<dim3(KK / 64, BB / 64), 256, 0, stream>>>(feat[br], ctx[br], T, KK);
    k_softmax_assign<<<BB, 256, 0, stream>>>(T, Yb, br == 0 ? outAssign : nullptr,
        sub[br][0][0], sub[br][0][1], sub[br][1][0], sub[br][1][1]);
    k_binary<<<(KK * BB) / 256, 256, 0, stream>>>(T, BIN, sub[br][2][0], sub[br][2][1]);
    k_rowsum<<<KK, 256, 0, stream>>>(BIN, RS);
    k_gemm_nn64<<<dim3(DD / 64, BB / 64, 1), 256, 0, stream>>>(Yb, ctx[br], aggn, DD, KK, BB, KK);
    k_gemm_nn64<<<dim3(DD / 64, KK / 64, 8), 256, 0, stream>>>(BIN, feat[br], CP, DD, BB, KK, 512);
    k_reduce_div<<<(KK * DD) / 256, 256, 0, stream>>>(CP, 8, KK * DD, RS, aggk);
    k_sumsq<<<256, 256, 0, stream>>>(aggn, BB * DD, PART);
    k_finalize_rsqrt<<<1, 256, 0, stream>>>(PART, SCAL + 3);
    k_scale<<<(BB * DD) / 256, 256, 0, stream>>>(aggn, SCAL + 3, BB * DD);
    k_sumsq<<<256, 256, 0, stream>>>(aggk, KK * DD, PART);
    k_finalize_rsqrt<<<1, 256, 0, stream>>>(PART, SCAL + 4);
    k_scale<<<(KK * DD) / 256, 256, 0, stream>>>(aggk, SCAL + 4, KK * DD);
  }

  k_queue<<<(QQ * DD) / 256, 256, 0, stream>>>(queue_k, SCAL + 1, QUEUE, kq0, kq1);
  k_sumsq<<<256, 256, 0, stream>>>(QUEUE, QQ * DD, PART);
  k_finalize_rsqrt<<<1, 256, 0, stream>>>(PART, SCAL + 2);   // fq

  // positives (f32)
  k_rowdot<<<BB, 256, 0, stream>>>(AGGN1, outAggn2, LPOSN);
  k_rowdot<<<KK, 256, 0, stream>>>(AGGK1, outAggk2, LPOSK);

  // bf16 conversions (T/Yb/BIN dead from here)
  k_cvt_bf16<<<(LL * DD) / 1024, 256, 0, stream>>>(queue_n, QNb, LL * DD);
  k_cvt_bf16<<<(QQ * DD) / 1024, 256, 0, stream>>>(QUEUE, QUb, QQ * DD);
  k_cvt_bf16<<<(BB * DD) / 1024, 256, 0, stream>>>(AGGN1, AGNb, BB * DD);
  k_cvt_bf16<<<(KK * DD) / 1024, 256, 0, stream>>>(AGGK1, AGKb, KK * DD);

  // loss_n: q = agg_n_1, negs = queue_n (sn folded). nxblk=32, nsplit=64 -> 2048 blocks.
  k_lse_mfma3<<<32 * 64, 256, 0, stream>>>(AGNb, QNb, SCAL + 0, LL / 64, BB, BB / 128, PSBUF);
  k_lse_partial<<<BB / 256, 256, 0, stream>>>(PSBUF, 64, LPOSN, BB, PNp);
  // loss_k: q = agg_k_1, negs = QUEUE (fq folded). nxblk=4, nsplit=128 -> 512 blocks.
  k_lse_mfma3<<<4 * 128, 256, 0, stream>>>(AGKb, QUb, SCAL + 2, QQ / 128, KK, KK / 128, PSBUF);
  k_lse_partial<<<KK / 256, 256, 0, stream>>>(PSBUF, 128, LPOSK, KK, PKp);
  k_loss_merge<<<1, 64, 0, stream>>>(PNp, BB / 256, BB, PKp, KK / 256, KK, outLoss);
}

// Round 7
// 673.372 us; speedup vs baseline: 1.0720x; 1.0032x over previous
//
#include <hip/hip_runtime.h>
#include <stdint.h>
#include <math.h>

typedef unsigned int u32;
typedef __attribute__((ext_vector_type(8))) short short8;
typedef __attribute__((ext_vector_type(4))) float f32x4;

#define BB 4096
#define DD 256
#define KK 512
#define LL 32768
#define QQ 8192

// ---------------- Threefry2x32 (JAX-exact, 20 rounds) ----------------
__host__ __device__ inline void tf2x32(u32 k0, u32 k1, u32 c0, u32 c1, u32& o0, u32& o1) {
  u32 ks2 = k0 ^ k1 ^ 0x1BD11BDAu;
  u32 x0 = c0 + k0, x1 = c1 + k1;
#define TF_R(r) { x0 += x1; x1 = ((x1 << (r)) | (x1 >> (32 - (r)))); x1 ^= x0; }
  TF_R(13) TF_R(15) TF_R(26) TF_R(6)
  x0 += k1; x1 += ks2 + 1u;
  TF_R(17) TF_R(29) TF_R(16) TF_R(24)
  x0 += ks2; x1 += k0 + 2u;
  TF_R(13) TF_R(15) TF_R(26) TF_R(6)
  x0 += k0; x1 += k1 + 3u;
  TF_R(17) TF_R(29) TF_R(16) TF_R(24)
  x0 += k1; x1 += ks2 + 4u;
  TF_R(13) TF_R(15) TF_R(26) TF_R(6)
  x0 += ks2; x1 += k0 + 5u;
#undef TF_R
  o0 = x0; o1 = x1;
}

__device__ inline u32 rbits32(u32 k0, u32 k1, u32 i) {
  u32 a, b;
  tf2x32(k0, k1, 0u, i, a, b);
  return a ^ b;
}

__device__ inline float u01f(u32 bits) {
  return __uint_as_float(0x3f800000u | (bits >> 9)) - 1.0f;
}

// f64-log gumbel: argmax-critical path only (bit-stable vs CPU libm)
__device__ inline float gumbel_at(u32 k0, u32 k1, u32 i) {
  float f = u01f(rbits32(k0, k1, i));
  float u = fmaxf(1e-20f, f + 1e-20f);
  float l1 = (float)log((double)u);
  float l2 = (float)log((double)(-l1));
  return -l2;
}

// fast f32 gumbel: continuous-output paths (y1 softmax) — ~1ulp logs
__device__ inline float gumbel_f32(u32 k0, u32 k1, u32 i) {
  float f = u01f(rbits32(k0, k1, i));
  float u = fmaxf(1e-20f, f + 1e-20f);
  float l1 = __logf(u);
  return -__logf(-l1);
}

// XLA f32 ErfInv (Giles polynomial)
__device__ inline float erfinv32(float x) {
  float w = -log1pf(-x * x);
  float p;
  if (w < 5.0f) {
    w -= 2.5f;
    p = 2.81022636e-08f;
    p = fmaf(p, w, 3.43273939e-07f);
    p = fmaf(p, w, -3.5233877e-06f);
    p = fmaf(p, w, -4.39150654e-06f);
    p = fmaf(p, w, 0.00021858087f);
    p = fmaf(p, w, -0.00125372503f);
    p = fmaf(p, w, -0.00417768164f);
    p = fmaf(p, w, 0.246640727f);
    p = fmaf(p, w, 1.50140941f);
  } else {
    w = sqrtf(w) - 3.0f;
    p = -0.000200214257f;
    p = fmaf(p, w, 0.000100950558f);
    p = fmaf(p, w, 0.00134934322f);
    p = fmaf(p, w, -0.00367342844f);
    p = fmaf(p, w, 0.00573950773f);
    p = fmaf(p, w, -0.0076224613f);
    p = fmaf(p, w, 0.00943887047f);
    p = fmaf(p, w, 1.00167406f);
    p = fmaf(p, w, 2.83297682f);
  }
  return p * x;
}

__device__ inline unsigned short f2bf(float f) {
  u32 u = __float_as_uint(f);
  u32 r = (u + 0x7FFFu + ((u >> 16) & 1u)) >> 16;
  return (unsigned short)r;
}

// ---------------- Reductions ----------------
__global__ __launch_bounds__(256)
void k_sumsq(const float* __restrict__ x, int n, float* __restrict__ partial) {
  __shared__ float sm[256];
  float s = 0.0f;
  for (int i = blockIdx.x * 256 + threadIdx.x; i < n; i += gridDim.x * 256) {
    float v = x[i]; s = fmaf(v, v, s);
  }
  sm[threadIdx.x] = s; __syncthreads();
  for (int off = 128; off > 0; off >>= 1) {
    if (threadIdx.x < off) sm[threadIdx.x] += sm[threadIdx.x + off];
    __syncthreads();
  }
  if (threadIdx.x == 0) partial[blockIdx.x] = sm[0];
}

__global__ __launch_bounds__(256)
void k_finalize_rsqrt(const float* __restrict__ partial, float* __restrict__ outv) {
  __shared__ float sm[256];
  int tid = threadIdx.x;
  sm[tid] = partial[tid];
  __syncthreads();
  for (int off = 128; off > 0; off >>= 1) {
    if (tid < off) sm[tid] += sm[tid + off];
    __syncthreads();
  }
  if (tid == 0) {
    float ssum = fmaxf(sm[0], 1e-12f);
    outv[0] = (float)(1.0 / sqrt((double)ssum));
  }
}

// ---------------- f32 GEMMs: 64x64 tile, 4x4 register tile ----------------
__global__ __launch_bounds__(256)
void k_gemm_nt64(const float* __restrict__ A, const float* __restrict__ Bm,
                 float* __restrict__ C, int N) {
  __shared__ float As[16][68], Bs[16][68];
  int tid = threadIdx.x;
  int tx = tid & 15, ty = tid >> 4;
  int rowBase = blockIdx.y * 64, colBase = blockIdx.x * 64;
  float c[4][4] = {};
  for (int kt = 0; kt < 256; kt += 16) {
#pragma unroll
    for (int q = 0; q < 4; q++) {
      int idx = tid + 256 * q;
      int kkx = idx & 15, rr = idx >> 4;
      As[kkx][rr] = A[(size_t)(rowBase + rr) * 256 + kt + kkx];
      Bs[kkx][rr] = Bm[(size_t)(colBase + rr) * 256 + kt + kkx];
    }
    __syncthreads();
#pragma unroll
    for (int kx = 0; kx < 16; kx++) {
      float4 a4 = *(const float4*)&As[kx][ty * 4];
      float4 b4 = *(const float4*)&Bs[kx][tx * 4];
      float av[4] = {a4.x, a4.y, a4.z, a4.w};
      float bv[4] = {b4.x, b4.y, b4.z, b4.w};
#pragma unroll
      for (int r = 0; r < 4; r++)
#pragma unroll
        for (int q = 0; q < 4; q++)
          c[r][q] = fmaf(av[r], bv[q], c[r][q]);
    }
    __syncthreads();
  }
#pragma unroll
  for (int r = 0; r < 4; r++)
#pragma unroll
    for (int q = 0; q < 4; q++)
      C[(size_t)(rowBase + ty * 4 + r) * N + colBase + tx * 4 + q] = c[r][q];
}

// C[M x N] = A[M x K] * Bm[K x N]; grid (N/64, M/64, S)
__global__ __launch_bounds__(256)
void k_gemm_nn64(const float* __restrict__ A, const float* __restrict__ Bm,
                 float* __restrict__ C, int N, int K, int M, int Kc) {
  __shared__ float As[16][68], Bs[16][68];
  int tid = threadIdx.x;
  int tx = tid & 15, ty = tid >> 4;
  int rowBase = blockIdx.y * 64, colBase = blockIdx.x * 64;
  int k0 = blockIdx.z * Kc;
  float c[4][4] = {};
  for (int kt = k0; kt < k0 + Kc; kt += 16) {
#pragma unroll
    for (int q = 0; q < 4; q++) {
      int idx = tid + 256 * q;
      int kkx = idx & 15, rr = idx >> 4;
      As[kkx][rr] = A[(size_t)(rowBase + rr) * K + kt + kkx];
      int kk = (tid >> 6) * 4 + q;
      int jj = tid & 63;
      Bs[kk][jj] = Bm[(size_t)(kt + kk) * N + colBase + jj];
    }
    __syncthreads();
#pragma unroll
    for (int kx = 0; kx < 16; kx++) {
      float4 a4 = *(const float4*)&As[kx][ty * 4];
      float4 b4 = *(const float4*)&Bs[kx][tx * 4];
      float av[4] = {a4.x, a4.y, a4.z, a4.w};
      float bv[4] = {b4.x, b4.y, b4.z, b4.w};
#pragma unroll
      for (int r = 0; r < 4; r++)
#pragma unroll
        for (int q = 0; q < 4; q++)
          c[r][q] = fmaf(av[r], bv[q], c[r][q]);
    }
    __syncthreads();
  }
  float* dst = C + (size_t)blockIdx.z * M * N;
#pragma unroll
  for (int r = 0; r < 4; r++)
#pragma unroll
    for (int q = 0; q < 4; q++)
      dst[(size_t)(rowBase + ty * 4 + r) * N + colBase + tx * 4 + q] = c[r][q];
}

__global__ __launch_bounds__(256)
void k_reduce_div(const float* __restrict__ Cp, int S, int MN,
                  const float* __restrict__ rs, float* __restrict__ out) {
  int i = blockIdx.x * 256 + threadIdx.x;
  if (i >= MN) return;
  float s = 0.0f;
  for (int t = 0; t < S; t++) s += Cp[(size_t)t * MN + i];
  out[i] = s / (rs[i >> 8] + 1e-8f);
}

// ---------------- softmax(y1) + hard argmax(y2), wave-shuffle reductions ----------------
__global__ __launch_bounds__(256)
void k_softmax_assign(const float* __restrict__ knT, float* __restrict__ Y,
                      float* __restrict__ assignOut,
                      u32 g1a, u32 g1b, u32 g2a, u32 g2b) {
  __shared__ float smA[4], smS[4], smM2[4], smS2[4], smV[4];
  __shared__ int smI[4];
  int b = blockIdx.x, tid = threadIdx.x;
  int lane = tid & 63, wid = tid >> 6;
  int i0 = b * KK + tid, i1 = i0 + 256;
  float x0 = knT[i0], x1 = knT[i1];

  // y1 path: fast f32 gumbels (feeds only continuous outputs)
  float z0 = x0 + gumbel_f32(g1a, g1b, (u32)i0);
  float z1 = x1 + gumbel_f32(g1a, g1b, (u32)i1);
  float wm = fmaxf(z0, z1);
#pragma unroll
  for (int off = 1; off < 64; off <<= 1) wm = fmaxf(wm, __shfl_xor(wm, off, 64));
  if (lane == 0) smA[wid] = wm;
  __syncthreads();
  float m = fmaxf(fmaxf(smA[0], smA[1]), fmaxf(smA[2], smA[3]));
  float e0 = expf(z0 - m), e1 = expf(z1 - m);
  float ws = e0 + e1;
#pragma unroll
  for (int off = 1; off < 64; off <<= 1) ws += __shfl_xor(ws, off, 64);
  if (lane == 0) smS[wid] = ws;
  __syncthreads();
  float s = (smS[0] + smS[1]) + (smS[2] + smS[3]);
  Y[i0] = e0 / s;
  Y[i1] = e1 / s;

  if (assignOut != nullptr) {
    // argmax path: keep f64-log gumbels (bit-stable, no discrete re-roll)
    float w0 = x0 + gumbel_at(g2a, g2b, (u32)i0);
    float w1 = x1 + gumbel_at(g2a, g2b, (u32)i1);
    float wm2 = fmaxf(w0, w1);
#pragma unroll
    for (int off = 1; off < 64; off <<= 1) wm2 = fmaxf(wm2, __shfl_xor(wm2, off, 64));
    if (lane == 0) smM2[wid] = wm2;
    __syncthreads();
    float m2 = fmaxf(fmaxf(smM2[0], smM2[1]), fmaxf(smM2[2], smM2[3]));
    float f0 = expf(w0 - m2), f1 = expf(w1 - m2);
    float ws2 = f0 + f1;
#pragma unroll
    for (int off = 1; off < 64; off <<= 1) ws2 += __shfl_xor(ws2, off, 64);
    if (lane == 0) smS2[wid] = ws2;
    __syncthreads();
    float s2 = (smS2[0] + smS2[1]) + (smS2[2] + smS2[3]);
    float y0 = f0 / s2, y1v = f1 / s2;
    float bv; int bi;
    if (y1v > y0) { bv = y1v; bi = tid + 256; } else { bv = y0; bi = tid; }
#pragma unroll
    for (int off = 1; off < 64; off <<= 1) {
      float ov = __shfl_xor(bv, off, 64);
      int oi = __shfl_xor(bi, off, 64);
      if (ov > bv || (ov == bv && oi < bi)) { bv = ov; bi = oi; }
    }
    if (lane == 0) { smV[wid] = bv; smI[wid] = bi; }
    __syncthreads();
    if (tid == 0) {
      float cv = smV[0]; int ci = smI[0];
#pragma unroll
      for (int t = 1; t < 4; t++) {
        if (smV[t] > cv || (smV[t] == cv && smI[t] < ci)) { cv = smV[t]; ci = smI[t]; }
      }
      assignOut[b] = (float)ci;
    }
  }
}

// ---------------- stochastic binary threshold ----------------
__global__ __launch_bounds__(256)
void k_binary(const float* __restrict__ knT, float* __restrict__ BIN, u32 k3a, u32 k3b) {
  int i = blockIdx.x * 256 + threadIdx.x;
  if (i >= KK * BB) return;
  int k = i / BB, b = i - k * BB;
  float x = knT[b * KK + k];
  float prob = (float)(1.0 / (1.0 + exp(-(double)x)));
  float eps = u01f(rbits32(k3a, k3b, (u32)i));
  BIN[i] = (prob > eps) ? 1.0f : 0.0f;
}

__global__ __launch_bounds__(256)
void k_rowsum(const float* __restrict__ BIN, float* __restrict__ rs) {
  __shared__ float sm[256];
  int k = blockIdx.x, tid = threadIdx.x;
  float s = 0.0f;
  for (int b = tid; b < BB; b += 256) s += BIN[k * BB + b];
  sm[tid] = s; __syncthreads();
  for (int off = 128; off > 0; off >>= 1) {
    if (tid < off) sm[tid] += sm[tid + off];
    __syncthreads();
  }
  if (tid == 0) rs[k] = sm[0];
}

__global__ __launch_bounds__(256)
void k_scale(float* __restrict__ x, const float* __restrict__ fac, int n) {
  int i = blockIdx.x * 256 + threadIdx.x;
  if (i < n) x[i] = x[i] * fac[0];
}

// ---------------- queue = 2*qk + 0.1*normal ----------------
__global__ __launch_bounds__(256)
void k_queue(const float* __restrict__ qk_in, const float* __restrict__ skp,
             float* __restrict__ QUEUE, u32 kqa, u32 kqb) {
  int i = blockIdx.x * 256 + threadIdx.x;
  if (i >= QQ * DD) return;
  float sk = skp[0];
  float qk = qk_in[i] * sk;
  float f = u01f(rbits32(kqa, kqb, (u32)i));
  const float lo = -0.99999994f;
  float u = fmaxf(lo, f * 2.0f + lo);
  float nv = 1.41421354f * erfinv32(u);
  float t = qk + 0.1f * nv;
  QUEUE[i] = t + qk;
}

__global__ __launch_bounds__(256)
void k_rowdot(const float* __restrict__ A, const float* __restrict__ Bv, float* __restrict__ outv) {
  __shared__ float sm[256];
  int r = blockIdx.x, tid = threadIdx.x;
  sm[tid] = A[r * 256 + tid] * Bv[r * 256 + tid];
  __syncthreads();
  for (int off = 128; off > 0; off >>= 1) {
    if (tid < off) sm[tid] += sm[tid + off];
    __syncthreads();
  }
  if (tid == 0) outv[r] = sm[0];
}

// ---------------- f32 -> bf16 conversion ----------------
__global__ __launch_bounds__(256)
void k_cvt_bf16(const float* __restrict__ src, unsigned short* __restrict__ dst, int n) {
  int i = (blockIdx.x * 256 + threadIdx.x) * 4;
  if (i >= n) return;
  float4 v = *(const float4*)(src + i);
  ushort2 a, b;
  a.x = f2bf(v.x); a.y = f2bf(v.y);
  b.x = f2bf(v.z); b.y = f2bf(v.w);
  *(ushort2*)(dst + i) = a;
  *(ushort2*)(dst + i + 2) = b;
}

// ---------------- fused bf16-MFMA GEMM + sum-exp, software-pipelined B ----------------
// |logits| < 0.01 (globally-l2-normalized operands) -> sum-exp needs no max.
// Double-buffered B in registers (named bufs, no runtime indexing): prefetch
// next 16 cols while MFMA+exp on current -> load->use distance = 1 compute
// block (~150cyc) x 3 waves/SIMD hides L2 latency (R6 diag: MfmaUtil 11% was
// zero-distance load->waitcnt->use serialization). sched_barrier(0) pins each
// prefetch group at the top of its phase. Lper must be a multiple of 32.
#define LSE_COMPUTE(BUF)                                                      \
  {                                                                           \
    _Pragma("unroll")                                                         \
    for (int ts = 0; ts < 2; ts++) {                                          \
      f32x4 acc = {0.f, 0.f, 0.f, 0.f};                                       \
      _Pragma("unroll")                                                       \
      for (int kf = 0; kf < 8; kf++)                                          \
        acc = __builtin_amdgcn_mfma_f32_16x16x32_bf16(afr[ts][kf], BUF[kf],   \
                                                      acc, 0, 0, 0);          \
      _Pragma("unroll")                                                       \
      for (int r = 0; r < 4; r++)                                             \
        s[ts][r] += __expf(acc[r] * lsc);                                     \
    }                                                                         \
  }

__global__ __launch_bounds__(256) __attribute__((amdgpu_waves_per_eu(3, 4)))
void k_lse_mfma4(const unsigned short* __restrict__ Qb, const unsigned short* __restrict__ Nb,
                 const float* __restrict__ scale_ptr, int Lper, int M, int nxblk,
                 float* __restrict__ ps) {
  int lin = blockIdx.x;
  int xb = (lin >> 3) % nxblk;
  int yb = (lin & 7) + 8 * (lin / (8 * nxblk));
  int tid = threadIdx.x;
  int wave = tid >> 6, lane = tid & 63;
  int rowBase = xb * 128 + wave * 32;
  float lsc = scale_ptr[0] / 0.07f;
  int lr = lane & 15;
  int lk = (lane >> 4) * 8;

  short8 afr[2][8];
#pragma unroll
  for (int ts = 0; ts < 2; ts++)
#pragma unroll
    for (int kf = 0; kf < 8; kf++)
      afr[ts][kf] = *(const short8*)(Qb + (size_t)(rowBase + ts * 16 + lr) * 256 + kf * 32 + lk);

  float s[2][4];
#pragma unroll
  for (int ts = 0; ts < 2; ts++)
#pragma unroll
    for (int r = 0; r < 4; r++) s[ts][r] = 0.0f;

  const unsigned short* bptr = Nb + (size_t)(yb * Lper + lr) * 256 + lk;
  short8 bufA[8], bufB[8];
  // prologue: prefetch cols [0,16)
#pragma unroll
  for (int kf = 0; kf < 8; kf++) bufA[kf] = *(const short8*)(bptr + kf * 32);
  __builtin_amdgcn_sched_barrier(0);

  for (int jj = 0; jj < Lper; jj += 32) {
    // prefetch cols [jj+16, jj+32)
#pragma unroll
    for (int kf = 0; kf < 8; kf++) bufB[kf] = *(const short8*)(bptr + 16 * 256 + kf * 32);
    __builtin_amdgcn_sched_barrier(0);
    LSE_COMPUTE(bufA);
    bptr += 32 * 256;
    if (jj + 32 < Lper) {
      // prefetch cols [jj+32, jj+48)
#pragma unroll
      for (int kf = 0; kf < 8; kf++) bufA[kf] = *(const short8*)(bptr + kf * 32);
      __builtin_amdgcn_sched_barrier(0);
    }
    LSE_COMPUTE(bufB);
  }

#pragma unroll
  for (int off = 1; off < 16; off <<= 1)
#pragma unroll
    for (int ts = 0; ts < 2; ts++)
#pragma unroll
      for (int r = 0; r < 4; r++)
        s[ts][r] += __shfl_xor(s[ts][r], off, 64);
  if (lr == 0) {
    int rg = (lane >> 4) * 4;
#pragma unroll
    for (int ts = 0; ts < 2; ts++)
#pragma unroll
      for (int r = 0; r < 4; r++)
        ps[(size_t)yb * M + rowBase + ts * 16 + rg + r] = s[ts][r];
  }
}

// partial row-LSE sums: grid nb blocks, one row per thread (M = nb*256)
__global__ __launch_bounds__(256)
void k_lse_partial(const float* __restrict__ ps, int nsplit,
                   const float* __restrict__ lpos, int M, float* __restrict__ partial) {
  __shared__ float sm[256];
  int tid = threadIdx.x;
  int row = blockIdx.x * 256 + tid;
  float s = 0.0f;
  for (int t = 0; t < nsplit; t++) s += ps[(size_t)t * M + row];
  float z0 = lpos[row] / 0.07f;
  s += expf(z0);
  float acc = logf(s) - z0;
  sm[tid] = acc; __syncthreads();
  for (int off = 128; off > 0; off >>= 1) {
    if (tid < off) sm[tid] += sm[tid + off];
    __syncthreads();
  }
  if (tid == 0) partial[blockIdx.x] = sm[0];
}

__global__ void k_loss_merge(const float* __restrict__ PN, int nN, int MN,
                             const float* __restrict__ PK, int nK, int MK,
                             float* __restrict__ outLoss) {
  if (threadIdx.x == 0) {
    float a = 0.0f, b = 0.0f;
    for (int i = 0; i < nN; i++) a += PN[i];
    for (int i = 0; i < nK; i++) b += PK[i];
    outLoss[0] = a / (float)MN + b / (float)MK;
  }
}

// ---------------- launch ----------------
extern "C" void kernel_launch(void* const* d_in, const int* in_sizes, int n_in,
                              void* d_out, int out_size, void* d_ws, size_t ws_size,
                              hipStream_t stream) {
  const float* feat[2] = {(const float*)d_in[0], (const float*)d_in[1]};
  const float* ctx[2]  = {(const float*)d_in[2], (const float*)d_in[3]};
  const float* queue_n = (const float*)d_in[4];
  const float* queue_k = (const float*)d_in[5];

  float* W = (float*)d_ws;
  size_t o = 0;
  float* T     = W + o; o += (size_t)BB * KK;
  float* Yb    = W + o; o += (size_t)BB * KK;   // also split-K partials (CP)
  float* BIN   = W + o; o += (size_t)KK * BB;
  float* AGGN1 = W + o; o += (size_t)BB * DD;
  float* AGGK1 = W + o; o += (size_t)KK * DD;
  float* QUEUE = W + o; o += (size_t)QQ * DD;
  float* RS    = W + o; o += KK;
  float* PART  = W + o; o += 256;
  float* SCAL  = W + o; o += 8;
  float* LPOSN = W + o; o += BB;
  float* LPOSK = W + o; o += KK;
  float* PNp   = W + o; o += 32;
  float* PKp   = W + o; o += 32;

  // bf16 loss operands overlay the dead T/Yb/BIN region
  unsigned short* QNb  = (unsigned short*)T;                 // 32768*256
  unsigned short* QUb  = QNb + (size_t)LL * DD;              // 8192*256
  unsigned short* AGNb = QUb + (size_t)QQ * DD;              // 4096*256
  unsigned short* AGKb = AGNb + (size_t)BB * DD;             // 512*256
  float* PSBUF = (float*)(AGKb + (size_t)KK * DD);
  float* CP = Yb;                                            // split-K partials

  float* out = (float*)d_out;
  float* outAssign = out;
  float* outAggn2  = out + BB;
  float* outAggk2  = out + BB + (size_t)BB * DD;
  float* outLoss   = out + BB + (size_t)BB * DD + (size_t)KK * DD;

  u32 kq0, kq1, kc[2][2];
  tf2x32(0u, 42u, 0u, 0u, kq0, kq1);
  tf2x32(0u, 42u, 0u, 1u, kc[0][0], kc[0][1]);
  tf2x32(0u, 42u, 0u, 2u, kc[1][0], kc[1][1]);
  u32 sub[2][3][2];
  for (int br = 0; br < 2; br++)
    for (int t = 0; t < 3; t++)
      tf2x32(kc[br][0], kc[br][1], 0u, (u32)t, sub[br][t][0], sub[br][t][1]);

  k_sumsq<<<256, 256, 0, stream>>>(queue_n, LL * DD, PART);
  k_finalize_rsqrt<<<1, 256, 0, stream>>>(PART, SCAL + 0);   // sn
  k_sumsq<<<256, 256, 0, stream>>>(queue_k, QQ * DD, PART);
  k_finalize_rsqrt<<<1, 256, 0, stream>>>(PART, SCAL + 1);   // sk

  for (int br = 0; br < 2; br++) {
    float* aggn = (br == 0) ? AGGN1 : outAggn2;
    float* aggk = (br == 0) ? AGGK1 : outAggk2;
    k_gemm_nt64<<<dim3(KK / 64, BB / 64), 256, 0, stream>>>(feat[br], ctx[br], T, KK);
    k_softmax_assign<<<BB, 256, 0, stream>>>(T, Yb, br == 0 ? outAssign : nullptr,
        sub[br][0][0], sub[br][0][1], sub[br][1][0], sub[br][1][1]);
    k_binary<<<(KK * BB) / 256, 256, 0, stream>>>(T, BIN, sub[br][2][0], sub[br][2][1]);
    k_rowsum<<<KK, 256, 0, stream>>>(BIN, RS);
    k_gemm_nn64<<<dim3(DD / 64, BB / 64, 1), 256, 0, stream>>>(Yb, ctx[br], aggn, DD, KK, BB, KK);
    k_gemm_nn64<<<dim3(DD / 64, KK / 64, 8), 256, 0, stream>>>(BIN, feat[br], CP, DD, BB, KK, 512);
    k_reduce_div<<<(KK * DD) / 256, 256, 0, stream>>>(CP, 8, KK * DD, RS, aggk);
    k_sumsq<<<256, 256, 0, stream>>>(aggn, BB * DD, PART);
    k_finalize_rsqrt<<<1, 256, 0, stream>>>(PART, SCAL + 3);
    k_scale<<<(BB * DD) / 256, 256, 0, stream>>>(aggn, SCAL + 3, BB * DD);
    k_sumsq<<<256, 256, 0, stream>>>(aggk, KK * DD, PART);
    k_finalize_rsqrt<<<1, 256, 0, stream>>>(PART, SCAL + 4);
    k_scale<<<(KK * DD) / 256, 256, 0, stream>>>(aggk, SCAL + 4, KK * DD);
  }

  k_queue<<<(QQ * DD) / 256, 256, 0, stream>>>(queue_k, SCAL + 1, QUEUE, kq0, kq1);
  k_sumsq<<<256, 256, 0, stream>>>(QUEUE, QQ * DD, PART);
  k_finalize_rsqrt<<<1, 256, 0, stream>>>(PART, SCAL + 2);   // fq

  // positives (f32)
  k_rowdot<<<BB, 256, 0, stream>>>(AGGN1, outAggn2, LPOSN);
  k_rowdot<<<KK, 256, 0, stream>>>(AGGK1, outAggk2, LPOSK);

  // bf16 conversions (T/Yb/BIN dead from here)
  k_cvt_bf16<<<(LL * DD) / 1024, 256, 0, stream>>>(queue_n, QNb, LL * DD);
  k_cvt_bf16<<<(QQ * DD) / 1024, 256, 0, stream>>>(QUEUE, QUb, QQ * DD);
  k_cvt_bf16<<<(BB * DD) / 1024, 256, 0, stream>>>(AGGN1, AGNb, BB * DD);
  k_cvt_bf16<<<(KK * DD) / 1024, 256, 0, stream>>>(AGGK1, AGKb, KK * DD);

  // loss_n: q = agg_n_1, negs = queue_n (sn folded). nxblk=32, nsplit=64 -> 2048 blocks, Lper=512.
  k_lse_mfma4<<<32 * 64, 256, 0, stream>>>(AGNb, QNb, SCAL + 0, LL / 64, BB, BB / 128, PSBUF);
  k_lse_partial<<<BB / 256, 256, 0, stream>>>(PSBUF, 64, LPOSN, BB, PNp);
  // loss_k: q = agg_k_1, negs = QUEUE (fq folded). nxblk=4, nsplit=128 -> 512 blocks, Lper=64.
  k_lse_mfma4<<<4 * 128, 256, 0, stream>>>(AGKb, QUb, SCAL + 2, QQ / 128, KK, KK / 128, PSBUF);
  k_lse_partial<<<KK / 256, 256, 0, stream>>>(PSBUF, 128, LPOSK, KK, PKp);
  k_loss_merge<<<1, 64, 0, stream>>>(PNp, BB / 256, BB, PKp, KK / 256, KK, outLoss);
}

// Round 8
// 493.680 us; speedup vs baseline: 1.4622x; 1.3640x over previous
//
#include <hip/hip_runtime.h>
#include <stdint.h>
#include <math.h>

typedef unsigned int u32;
typedef __attribute__((ext_vector_type(8))) short short8;
typedef __attribute__((ext_vector_type(4))) float f32x4;

#define BB 4096
#define DD 256
#define KK 512
#define LL 32768
#define QQ 8192

// ---------------- Threefry2x32 (JAX-exact, 20 rounds) ----------------
__host__ __device__ inline void tf2x32(u32 k0, u32 k1, u32 c0, u32 c1, u32& o0, u32& o1) {
  u32 ks2 = k0 ^ k1 ^ 0x1BD11BDAu;
  u32 x0 = c0 + k0, x1 = c1 + k1;
#define TF_R(r) { x0 += x1; x1 = ((x1 << (r)) | (x1 >> (32 - (r)))); x1 ^= x0; }
  TF_R(13) TF_R(15) TF_R(26) TF_R(6)
  x0 += k1; x1 += ks2 + 1u;
  TF_R(17) TF_R(29) TF_R(16) TF_R(24)
  x0 += ks2; x1 += k0 + 2u;
  TF_R(13) TF_R(15) TF_R(26) TF_R(6)
  x0 += k0; x1 += k1 + 3u;
  TF_R(17) TF_R(29) TF_R(16) TF_R(24)
  x0 += k1; x1 += ks2 + 4u;
  TF_R(13) TF_R(15) TF_R(26) TF_R(6)
  x0 += ks2; x1 += k0 + 5u;
#undef TF_R
  o0 = x0; o1 = x1;
}

__device__ inline u32 rbits32(u32 k0, u32 k1, u32 i) {
  u32 a, b;
  tf2x32(k0, k1, 0u, i, a, b);
  return a ^ b;
}

__device__ inline float u01f(u32 bits) {
  return __uint_as_float(0x3f800000u | (bits >> 9)) - 1.0f;
}

// f64-log gumbel: argmax-critical path only (bit-stable vs CPU libm)
__device__ inline float gumbel_at(u32 k0, u32 k1, u32 i) {
  float f = u01f(rbits32(k0, k1, i));
  float u = fmaxf(1e-20f, f + 1e-20f);
  float l1 = (float)log((double)u);
  float l2 = (float)log((double)(-l1));
  return -l2;
}

// fast f32 gumbel: continuous-output paths (y1 softmax)
__device__ inline float gumbel_f32(u32 k0, u32 k1, u32 i) {
  float f = u01f(rbits32(k0, k1, i));
  float u = fmaxf(1e-20f, f + 1e-20f);
  float l1 = __logf(u);
  return -__logf(-l1);
}

// XLA f32 ErfInv (Giles polynomial)
__device__ inline float erfinv32(float x) {
  float w = -log1pf(-x * x);
  float p;
  if (w < 5.0f) {
    w -= 2.5f;
    p = 2.81022636e-08f;
    p = fmaf(p, w, 3.43273939e-07f);
    p = fmaf(p, w, -3.5233877e-06f);
    p = fmaf(p, w, -4.39150654e-06f);
    p = fmaf(p, w, 0.00021858087f);
    p = fmaf(p, w, -0.00125372503f);
    p = fmaf(p, w, -0.00417768164f);
    p = fmaf(p, w, 0.246640727f);
    p = fmaf(p, w, 1.50140941f);
  } else {
    w = sqrtf(w) - 3.0f;
    p = -0.000200214257f;
    p = fmaf(p, w, 0.000100950558f);
    p = fmaf(p, w, 0.00134934322f);
    p = fmaf(p, w, -0.00367342844f);
    p = fmaf(p, w, 0.00573950773f);
    p = fmaf(p, w, -0.0076224613f);
    p = fmaf(p, w, 0.00943887047f);
    p = fmaf(p, w, 1.00167406f);
    p = fmaf(p, w, 2.83297682f);
  }
  return p * x;
}

__device__ inline unsigned short f2bf(float f) {
  u32 u = __float_as_uint(f);
  u32 r = (u + 0x7FFFu + ((u >> 16) & 1u)) >> 16;
  return (unsigned short)r;
}

// ---------------- queue_k raw sumsq (for sk) ----------------
__global__ __launch_bounds__(256)
void k_sumsq(const float* __restrict__ x, int n, float* __restrict__ partial) {
  __shared__ float sm[256];
  float s = 0.0f;
  for (int i = blockIdx.x * 256 + threadIdx.x; i < n; i += gridDim.x * 256) {
    float v = x[i]; s = fmaf(v, v, s);
  }
  sm[threadIdx.x] = s; __syncthreads();
  for (int off = 128; off > 0; off >>= 1) {
    if (threadIdx.x < off) sm[threadIdx.x] += sm[threadIdx.x + off];
    __syncthreads();
  }
  if (threadIdx.x == 0) partial[blockIdx.x] = sm[0];
}

// ---------------- queue_n -> bf16 + sumsq partials (fused) ----------------
__global__ __launch_bounds__(256)
void k_prep_n(const float* __restrict__ src, unsigned short* __restrict__ dst,
              float* __restrict__ partial) {
  __shared__ float sm[256];
  int tid = threadIdx.x;
  float s = 0.0f;
  const int n = LL * DD;
  for (int i = (blockIdx.x * 256 + tid) * 4; i < n; i += 256 * 256 * 4) {
    float4 v = *(const float4*)(src + i);
    s = fmaf(v.x, v.x, s); s = fmaf(v.y, v.y, s);
    s = fmaf(v.z, v.z, s); s = fmaf(v.w, v.w, s);
    ushort2 a, b;
    a.x = f2bf(v.x); a.y = f2bf(v.y);
    b.x = f2bf(v.z); b.y = f2bf(v.w);
    *(ushort2*)(dst + i) = a;
    *(ushort2*)(dst + i + 2) = b;
  }
  sm[tid] = s; __syncthreads();
  for (int off = 128; off > 0; off >>= 1) {
    if (tid < off) sm[tid] += sm[tid + off];
    __syncthreads();
  }
  if (tid == 0) partial[blockIdx.x] = sm[0];
}

// ---------------- queue = 2*l2n(qk) + 0.1*normal -> bf16 + sumsq (fused) ----------------
__global__ __launch_bounds__(256)
void k_queue_fused(const float* __restrict__ qk_in, const float* __restrict__ partK,
                   unsigned short* __restrict__ dst, float* __restrict__ partial,
                   u32 kqa, u32 kqb) {
  __shared__ float sm[256];
  int tid = threadIdx.x;
  sm[tid] = partK[tid]; __syncthreads();
  for (int off = 128; off > 0; off >>= 1) {
    if (tid < off) sm[tid] += sm[tid + off];
    __syncthreads();
  }
  float sk = (float)(1.0 / sqrt((double)fmaxf(sm[0], 1e-12f)));
  __syncthreads();

  int i0 = (blockIdx.x * 256 + tid) * 4;
  float4 v = *(const float4*)(qk_in + i0);
  float vin[4] = {v.x, v.y, v.z, v.w};
  unsigned short h[4];
  float s = 0.0f;
  const float lo = -0.99999994f;
#pragma unroll
  for (int e = 0; e < 4; e++) {
    float qk = vin[e] * sk;
    float f = u01f(rbits32(kqa, kqb, (u32)(i0 + e)));
    float u = fmaxf(lo, f * 2.0f + lo);
    float nv = 1.41421354f * erfinv32(u);
    float t = qk + 0.1f * nv;
    float val = t + qk;
    s = fmaf(val, val, s);
    h[e] = f2bf(val);
  }
  ushort2 a, b;
  a.x = h[0]; a.y = h[1]; b.x = h[2]; b.y = h[3];
  *(ushort2*)(dst + i0) = a;
  *(ushort2*)(dst + i0 + 2) = b;

  sm[tid] = s; __syncthreads();
  for (int off = 128; off > 0; off >>= 1) {
    if (tid < off) sm[tid] += sm[tid + off];
    __syncthreads();
  }
  if (tid == 0) partial[blockIdx.x] = sm[0];
}

// ---------------- f32 GEMMs: 64x64 tile, 4x4 register tile ----------------
__global__ __launch_bounds__(256)
void k_gemm_nt64(const float* __restrict__ A, const float* __restrict__ Bm,
                 float* __restrict__ C, int N) {
  __shared__ float As[16][68], Bs[16][68];
  int tid = threadIdx.x;
  int tx = tid & 15, ty = tid >> 4;
  int rowBase = blockIdx.y * 64, colBase = blockIdx.x * 64;
  float c[4][4] = {};
  for (int kt = 0; kt < 256; kt += 16) {
#pragma unroll
    for (int q = 0; q < 4; q++) {
      int idx = tid + 256 * q;
      int kkx = idx & 15, rr = idx >> 4;
      As[kkx][rr] = A[(size_t)(rowBase + rr) * 256 + kt + kkx];
      Bs[kkx][rr] = Bm[(size_t)(colBase + rr) * 256 + kt + kkx];
    }
    __syncthreads();
#pragma unroll
    for (int kx = 0; kx < 16; kx++) {
      float4 a4 = *(const float4*)&As[kx][ty * 4];
      float4 b4 = *(const float4*)&Bs[kx][tx * 4];
      float av[4] = {a4.x, a4.y, a4.z, a4.w};
      float bv[4] = {b4.x, b4.y, b4.z, b4.w};
#pragma unroll
      for (int r = 0; r < 4; r++)
#pragma unroll
        for (int q = 0; q < 4; q++)
          c[r][q] = fmaf(av[r], bv[q], c[r][q]);
    }
    __syncthreads();
  }
#pragma unroll
  for (int r = 0; r < 4; r++)
#pragma unroll
    for (int q = 0; q < 4; q++)
      C[(size_t)(rowBase + ty * 4 + r) * N + colBase + tx * 4 + q] = c[r][q];
}

// C[M x N] = A[M x K] * Bm[K x N]; grid (N/64, M/64, S). Optional sumsq partials.
__global__ __launch_bounds__(256)
void k_gemm_nn64(const float* __restrict__ A, const float* __restrict__ Bm,
                 float* __restrict__ C, int N, int K, int M, int Kc,
                 float* __restrict__ sqp) {
  __shared__ float As[16][68], Bs[16][68];
  __shared__ float sq[256];
  int tid = threadIdx.x;
  int tx = tid & 15, ty = tid >> 4;
  int rowBase = blockIdx.y * 64, colBase = blockIdx.x * 64;
  int k0 = blockIdx.z * Kc;
  float c[4][4] = {};
  for (int kt = k0; kt < k0 + Kc; kt += 16) {
#pragma unroll
    for (int q = 0; q < 4; q++) {
      int idx = tid + 256 * q;
      int kkx = idx & 15, rr = idx >> 4;
      As[kkx][rr] = A[(size_t)(rowBase + rr) * K + kt + kkx];
      int kk = (tid >> 6) * 4 + q;
      int jj = tid & 63;
      Bs[kk][jj] = Bm[(size_t)(kt + kk) * N + colBase + jj];
    }
    __syncthreads();
#pragma unroll
    for (int kx = 0; kx < 16; kx++) {
      float4 a4 = *(const float4*)&As[kx][ty * 4];
      float4 b4 = *(const float4*)&Bs[kx][tx * 4];
      float av[4] = {a4.x, a4.y, a4.z, a4.w};
      float bv[4] = {b4.x, b4.y, b4.z, b4.w};
#pragma unroll
      for (int r = 0; r < 4; r++)
#pragma unroll
        for (int q = 0; q < 4; q++)
          c[r][q] = fmaf(av[r], bv[q], c[r][q]);
    }
    __syncthreads();
  }
  float* dst = C + (size_t)blockIdx.z * M * N;
#pragma unroll
  for (int r = 0; r < 4; r++)
#pragma unroll
    for (int q = 0; q < 4; q++)
      dst[(size_t)(rowBase + ty * 4 + r) * N + colBase + tx * 4 + q] = c[r][q];
  if (sqp != nullptr) {
    float ls = 0.0f;
#pragma unroll
    for (int r = 0; r < 4; r++)
#pragma unroll
      for (int q = 0; q < 4; q++) ls = fmaf(c[r][q], c[r][q], ls);
    sq[tid] = ls; __syncthreads();
    for (int off = 128; off > 0; off >>= 1) {
      if (tid < off) sq[tid] += sq[tid + off];
      __syncthreads();
    }
    if (tid == 0) sqp[blockIdx.y * gridDim.x + blockIdx.x] = sq[0];
  }
}

// sum split-K partials, divide by row-sum, emit sumsq partials
__global__ __launch_bounds__(256)
void k_reduce_div(const float* __restrict__ Cp, int S, int MN,
                  const float* __restrict__ rs, float* __restrict__ out,
                  float* __restrict__ sqp) {
  __shared__ float sq[256];
  int tid = threadIdx.x;
  int i = blockIdx.x * 256 + tid;
  float s = 0.0f;
  for (int t = 0; t < S; t++) s += Cp[(size_t)t * MN + i];
  float v = s / (rs[i >> 8] + 1e-8f);
  out[i] = v;
  sq[tid] = v * v; __syncthreads();
  for (int off = 128; off > 0; off >>= 1) {
    if (tid < off) sq[tid] += sq[tid + off];
    __syncthreads();
  }
  if (tid == 0) sqp[blockIdx.x] = sq[0];
}

// reduce sumsq partials -> rsqrt factor; scale in place; optional bf16 out
__global__ __launch_bounds__(256)
void k_scale_cvt(float* __restrict__ data, unsigned short* __restrict__ dstBf,
                 const float* __restrict__ sqp, int np, int n) {
  __shared__ float sm[256];
  int tid = threadIdx.x;
  float a = 0.0f;
  for (int i = tid; i < np; i += 256) a += sqp[i];
  sm[tid] = a; __syncthreads();
  for (int off = 128; off > 0; off >>= 1) {
    if (tid < off) sm[tid] += sm[tid + off];
    __syncthreads();
  }
  float f = (float)(1.0 / sqrt((double)fmaxf(sm[0], 1e-12f)));
  int i = (blockIdx.x * 256 + tid) * 4;
  if (i < n) {
    float4 v = *(const float4*)(data + i);
    v.x *= f; v.y *= f; v.z *= f; v.w *= f;
    *(float4*)(data + i) = v;
    if (dstBf != nullptr) {
      ushort2 p, q;
      p.x = f2bf(v.x); p.y = f2bf(v.y);
      q.x = f2bf(v.z); q.y = f2bf(v.w);
      *(ushort2*)(dstBf + i) = p;
      *(ushort2*)(dstBf + i + 2) = q;
    }
  }
}

// ---------------- softmax(y1) + hard argmax(y2), wave-shuffle reductions ----------------
__global__ __launch_bounds__(256)
void k_softmax_assign(const float* __restrict__ knT, float* __restrict__ Y,
                      float* __restrict__ assignOut,
                      u32 g1a, u32 g1b, u32 g2a, u32 g2b) {
  __shared__ float smA[4], smS[4], smM2[4], smS2[4], smV[4];
  __shared__ int smI[4];
  int b = blockIdx.x, tid = threadIdx.x;
  int lane = tid & 63, wid = tid >> 6;
  int i0 = b * KK + tid, i1 = i0 + 256;
  float x0 = knT[i0], x1 = knT[i1];

  // y1 path: fast f32 gumbels (feeds only continuous outputs)
  float z0 = x0 + gumbel_f32(g1a, g1b, (u32)i0);
  float z1 = x1 + gumbel_f32(g1a, g1b, (u32)i1);
  float wm = fmaxf(z0, z1);
#pragma unroll
  for (int off = 1; off < 64; off <<= 1) wm = fmaxf(wm, __shfl_xor(wm, off, 64));
  if (lane == 0) smA[wid] = wm;
  __syncthreads();
  float m = fmaxf(fmaxf(smA[0], smA[1]), fmaxf(smA[2], smA[3]));
  float e0 = expf(z0 - m), e1 = expf(z1 - m);
  float ws = e0 + e1;
#pragma unroll
  for (int off = 1; off < 64; off <<= 1) ws += __shfl_xor(ws, off, 64);
  if (lane == 0) smS[wid] = ws;
  __syncthreads();
  float s = (smS[0] + smS[1]) + (smS[2] + smS[3]);
  Y[i0] = e0 / s;
  Y[i1] = e1 / s;

  if (assignOut != nullptr) {
    // argmax path: f64-log gumbels, bit-identical to prior passing rounds
    float w0 = x0 + gumbel_at(g2a, g2b, (u32)i0);
    float w1 = x1 + gumbel_at(g2a, g2b, (u32)i1);
    float wm2 = fmaxf(w0, w1);
#pragma unroll
    for (int off = 1; off < 64; off <<= 1) wm2 = fmaxf(wm2, __shfl_xor(wm2, off, 64));
    if (lane == 0) smM2[wid] = wm2;
    __syncthreads();
    float m2 = fmaxf(fmaxf(smM2[0], smM2[1]), fmaxf(smM2[2], smM2[3]));
    float f0 = expf(w0 - m2), f1 = expf(w1 - m2);
    float ws2 = f0 + f1;
#pragma unroll
    for (int off = 1; off < 64; off <<= 1) ws2 += __shfl_xor(ws2, off, 64);
    if (lane == 0) smS2[wid] = ws2;
    __syncthreads();
    float s2 = (smS2[0] + smS2[1]) + (smS2[2] + smS2[3]);
    float y0 = f0 / s2, y1v = f1 / s2;
    float bv; int bi;
    if (y1v > y0) { bv = y1v; bi = tid + 256; } else { bv = y0; bi = tid; }
#pragma unroll
    for (int off = 1; off < 64; off <<= 1) {
      float ov = __shfl_xor(bv, off, 64);
      int oi = __shfl_xor(bi, off, 64);
      if (ov > bv || (ov == bv && oi < bi)) { bv = ov; bi = oi; }
    }
    if (lane == 0) { smV[wid] = bv; smI[wid] = bi; }
    __syncthreads();
    if (tid == 0) {
      float cv = smV[0]; int ci = smI[0];
#pragma unroll
      for (int t = 1; t < 4; t++) {
        if (smV[t] > cv || (smV[t] == cv && smI[t] < ci)) { cv = smV[t]; ci = smI[t]; }
      }
      assignOut[b] = (float)ci;
    }
  }
}

// ---------------- stochastic binary threshold + fused row-sum ----------------
// One block spans 256 consecutive b of a single k (BB=4096). Row counts are
// whole numbers < 2^24 -> float atomicAdd is exact & order-independent.
__global__ __launch_bounds__(256)
void k_binary(const float* __restrict__ knT, float* __restrict__ BIN,
              float* __restrict__ rs, u32 k3a, u32 k3b) {
  __shared__ float sm[256];
  int tid = threadIdx.x;
  int i = blockIdx.x * 256 + tid;
  int k = i >> 12, b = i & 4095;
  float x = knT[b * KK + k];
  float prob = (float)(1.0 / (1.0 + exp(-(double)x)));
  float eps = u01f(rbits32(k3a, k3b, (u32)i));
  float bin = (prob > eps) ? 1.0f : 0.0f;
  BIN[i] = bin;
  sm[tid] = bin; __syncthreads();
  for (int off = 128; off > 0; off >>= 1) {
    if (tid < off) sm[tid] += sm[tid + off];
    __syncthreads();
  }
  if (tid == 0) atomicAdd(rs + k, sm[0]);
}

// ---------------- positives: 4 rows/block, wave-shuffle ----------------
__global__ __launch_bounds__(256)
void k_rowdot(const float* __restrict__ A, const float* __restrict__ Bv,
              float* __restrict__ outv) {
  int wave = threadIdx.x >> 6, lane = threadIdx.x & 63;
  int r = blockIdx.x * 4 + wave;
  float4 a = *(const float4*)(A + (size_t)r * 256 + lane * 4);
  float4 b = *(const float4*)(Bv + (size_t)r * 256 + lane * 4);
  float s = a.x * b.x + a.y * b.y + a.z * b.z + a.w * b.w;
#pragma unroll
  for (int off = 1; off < 64; off <<= 1) s += __shfl_xor(s, off, 64);
  if (lane == 0) outv[r] = s;
}

// ---------------- fused bf16-MFMA GEMM + sum-exp (R3 config: 64 rows/wave) ----------------
// |logits| < 0.01 (globally-l2-normalized operands) -> sum-exp needs no max.
// grid (M/256, nsplit), 4 waves x 64 rows. Logit scale computed in-block from
// sumsq partials (finalize fused). ps layout: [nsplit][M].
__global__ __launch_bounds__(256)
void k_lse_mfma2(const unsigned short* __restrict__ Qb, const unsigned short* __restrict__ Nb,
                 const float* __restrict__ sqp, int np, int Lper, int M,
                 float* __restrict__ ps) {
  __shared__ float red[256];
  int tid = threadIdx.x;
  float a = 0.0f;
  for (int i = tid; i < np; i += 256) a += sqp[i];
  red[tid] = a; __syncthreads();
  for (int off = 128; off > 0; off >>= 1) {
    if (tid < off) red[tid] += red[tid + off];
    __syncthreads();
  }
  float sr = (float)(1.0 / sqrt((double)fmaxf(red[0], 1e-12f)));
  float lsc = sr / 0.07f;

  int wave = tid >> 6, lane = tid & 63;
  int rowBase = blockIdx.x * 256 + wave * 64;
  int j0 = blockIdx.y * Lper;
  int lr = lane & 15;
  int lk = (lane >> 4) * 8;

  short8 afr[4][8];
#pragma unroll
  for (int ts = 0; ts < 4; ts++)
#pragma unroll
    for (int kf = 0; kf < 8; kf++)
      afr[ts][kf] = *(const short8*)(Qb + (size_t)(rowBase + ts * 16 + lr) * 256 + kf * 32 + lk);

  float s[4][4];
#pragma unroll
  for (int ts = 0; ts < 4; ts++)
#pragma unroll
    for (int r = 0; r < 4; r++) s[ts][r] = 0.0f;

  for (int j = 0; j < Lper; j += 16) {
    const unsigned short* bbase = Nb + (size_t)(j0 + j + lr) * 256 + lk;
    short8 bfr[8];
#pragma unroll
    for (int kf = 0; kf < 8; kf++) bfr[kf] = *(const short8*)(bbase + kf * 32);
#pragma unroll
    for (int ts = 0; ts < 4; ts++) {
      f32x4 acc = {0.f, 0.f, 0.f, 0.f};
#pragma unroll
      for (int kf = 0; kf < 8; kf++)
        acc = __builtin_amdgcn_mfma_f32_16x16x32_bf16(afr[ts][kf], bfr[kf], acc, 0, 0, 0);
#pragma unroll
      for (int r = 0; r < 4; r++)
        s[ts][r] += __expf(acc[r] * lsc);
    }
  }
#pragma unroll
  for (int off = 1; off < 16; off <<= 1)
#pragma unroll
    for (int ts = 0; ts < 4; ts++)
#pragma unroll
      for (int r = 0; r < 4; r++)
        s[ts][r] += __shfl_xor(s[ts][r], off, 64);
  if (lr == 0) {
    int rg = (lane >> 4) * 4;
#pragma unroll
    for (int ts = 0; ts < 4; ts++)
#pragma unroll
      for (int r = 0; r < 4; r++)
        ps[(size_t)blockIdx.y * M + rowBase + ts * 16 + rg + r] = s[ts][r];
  }
}

// partial row-LSE sums: grid nb blocks, one row per thread (M = nb*256)
__global__ __launch_bounds__(256)
void k_lse_partial(const float* __restrict__ ps, int nsplit,
                   const float* __restrict__ lpos, int M, float* __restrict__ partial) {
  __shared__ float sm[256];
  int tid = threadIdx.x;
  int row = blockIdx.x * 256 + tid;
  float s = 0.0f;
  for (int t = 0; t < nsplit; t++) s += ps[(size_t)t * M + row];
  float z0 = lpos[row] / 0.07f;
  s += expf(z0);
  float acc = logf(s) - z0;
  sm[tid] = acc; __syncthreads();
  for (int off = 128; off > 0; off >>= 1) {
    if (tid < off) sm[tid] += sm[tid + off];
    __syncthreads();
  }
  if (tid == 0) partial[blockIdx.x] = sm[0];
}

__global__ void k_loss_merge(const float* __restrict__ PN, int nN, int MN,
                             const float* __restrict__ PK, int nK, int MK,
                             float* __restrict__ outLoss) {
  if (threadIdx.x == 0) {
    float a = 0.0f, b = 0.0f;
    for (int i = 0; i < nN; i++) a += PN[i];
    for (int i = 0; i < nK; i++) b += PK[i];
    outLoss[0] = a / (float)MN + b / (float)MK;
  }
}

// ---------------- launch ----------------
extern "C" void kernel_launch(void* const* d_in, const int* in_sizes, int n_in,
                              void* d_out, int out_size, void* d_ws, size_t ws_size,
                              hipStream_t stream) {
  const float* feat[2] = {(const float*)d_in[0], (const float*)d_in[1]};
  const float* ctx[2]  = {(const float*)d_in[2], (const float*)d_in[3]};
  const float* queue_n = (const float*)d_in[4];
  const float* queue_k = (const float*)d_in[5];

  float* W = (float*)d_ws;
  size_t o = 0;
  float* T     = W + o; o += (size_t)BB * KK;   // 2M floats
  float* Yb    = W + o; o += (size_t)BB * KK;   // 2M (also split-K partials CP)
  float* BIN   = W + o; o += (size_t)KK * BB;   // 2M
  float* AGGN1 = W + o; o += (size_t)BB * DD;   // 1M
  float* AGGK1 = W + o; o += (size_t)KK * DD;   // 128K
  float* FREE  = W + o; o += (size_t)QQ * DD;   // 2M floats repurposed region
  float* RS    = W + o; o += KK;
  float* LPOSN = W + o; o += BB;
  float* LPOSK = W + o; o += KK;
  float* PNp   = W + o; o += 32;
  float* PKp   = W + o; o += 32;

  // QNb/QUb overlay the dead T/Yb/BIN region (only used after branch loop)
  unsigned short* QNb  = (unsigned short*)T;          // 8.4M shorts (16.8MB)
  unsigned short* QUb  = QNb + (size_t)LL * DD;       // 2.1M shorts (4.2MB); total 21MB <= 24MB
  // FREE region (8MB): bf16 agg operands + PSBUF + partial buffers
  unsigned short* AGNb = (unsigned short*)FREE;                    // 1.05M shorts
  unsigned short* AGKb = AGNb + (size_t)BB * DD;                   // 131K shorts
  float* PSBUF = (float*)(AGKb + (size_t)KK * DD);                 // up to 131072 floats
  float* PART_N = PSBUF + 32 * BB;                                 // 256
  float* PART_K = PART_N + 256;                                    // 256
  float* PART_Q = PART_K + 256;                                    // 2048
  float* SQPN   = PART_Q + 2048;                                   // 256
  float* SQPK   = SQPN + 256;                                      // 512

  float* out = (float*)d_out;
  float* outAssign = out;
  float* outAggn2  = out + BB;
  float* outAggk2  = out + BB + (size_t)BB * DD;
  float* outLoss   = out + BB + (size_t)BB * DD + (size_t)KK * DD;

  u32 kq0, kq1, kc[2][2];
  tf2x32(0u, 42u, 0u, 0u, kq0, kq1);
  tf2x32(0u, 42u, 0u, 1u, kc[0][0], kc[0][1]);
  tf2x32(0u, 42u, 0u, 2u, kc[1][0], kc[1][1]);
  u32 sub[2][3][2];
  for (int br = 0; br < 2; br++)
    for (int t = 0; t < 3; t++)
      tf2x32(kc[br][0], kc[br][1], 0u, (u32)t, sub[br][t][0], sub[br][t][1]);

  // sk partials (queue_k raw)
  k_sumsq<<<256, 256, 0, stream>>>(queue_k, QQ * DD, PART_K);

  for (int br = 0; br < 2; br++) {
    float* aggn = (br == 0) ? AGGN1 : outAggn2;
    float* aggk = (br == 0) ? AGGK1 : outAggk2;
    hipMemsetAsync(RS, 0, KK * sizeof(float), stream);
    k_gemm_nt64<<<dim3(KK / 64, BB / 64), 256, 0, stream>>>(feat[br], ctx[br], T, KK);
    k_softmax_assign<<<BB, 256, 0, stream>>>(T, Yb, br == 0 ? outAssign : nullptr,
        sub[br][0][0], sub[br][0][1], sub[br][1][0], sub[br][1][1]);
    k_binary<<<(KK * BB) / 256, 256, 0, stream>>>(T, BIN, RS, sub[br][2][0], sub[br][2][1]);
    k_gemm_nn64<<<dim3(DD / 64, BB / 64, 1), 256, 0, stream>>>(Yb, ctx[br], aggn, DD, KK, BB, KK, SQPN);
    k_gemm_nn64<<<dim3(DD / 64, KK / 64, 8), 256, 0, stream>>>(BIN, feat[br], Yb, DD, BB, KK, 512, nullptr);
    k_reduce_div<<<(KK * DD) / 256, 256, 0, stream>>>(Yb, 8, KK * DD, RS, aggk, SQPK);
    k_scale_cvt<<<(BB * DD) / 1024, 256, 0, stream>>>(aggn, br == 0 ? AGNb : nullptr, SQPN, 256, BB * DD);
    k_scale_cvt<<<(KK * DD) / 1024, 256, 0, stream>>>(aggk, br == 0 ? AGKb : nullptr, SQPK, 512, KK * DD);
  }

  // loss operand prep (T/Yb/BIN dead from here)
  k_prep_n<<<256, 256, 0, stream>>>(queue_n, QNb, PART_N);
  k_queue_fused<<<(QQ * DD) / 1024, 256, 0, stream>>>(queue_k, PART_K, QUb, PART_Q, kq0, kq1);

  // positives
  k_rowdot<<<BB / 4, 256, 0, stream>>>(AGGN1, outAggn2, LPOSN);
  k_rowdot<<<KK / 4, 256, 0, stream>>>(AGGK1, outAggk2, LPOSK);

  // loss_n: nsplit=32, Lper=1024 (R3 config)
  k_lse_mfma2<<<dim3(BB / 256, 32), 256, 0, stream>>>(AGNb, QNb, PART_N, 256, LL / 32, BB, PSBUF);
  k_lse_partial<<<BB / 256, 256, 0, stream>>>(PSBUF, 32, LPOSN, BB, PNp);
  // loss_k: nsplit=128, Lper=64
  k_lse_mfma2<<<dim3(KK / 256, 128), 256, 0, stream>>>(AGKb, QUb, PART_Q, 2048, QQ / 128, KK, PSBUF);
  k_lse_partial<<<KK / 256, 256, 0, stream>>>(PSBUF, 128, LPOSK, KK, PKp);
  k_loss_merge<<<1, 64, 0, stream>>>(PNp, BB / 256, BB, PKp, KK / 256, KK, outLoss);
}

// Round 9
// 480.993 us; speedup vs baseline: 1.5007x; 1.0264x over previous
//
#include <hip/hip_runtime.h>
#include <stdint.h>
#include <math.h>

typedef unsigned int u32;
typedef __attribute__((ext_vector_type(8))) short short8;
typedef __attribute__((ext_vector_type(4))) float f32x4;

#define BB 4096
#define DD 256
#define KK 512
#define LL 32768
#define QQ 8192

// ---------------- Threefry2x32 (JAX-exact, 20 rounds) ----------------
__host__ __device__ inline void tf2x32(u32 k0, u32 k1, u32 c0, u32 c1, u32& o0, u32& o1) {
  u32 ks2 = k0 ^ k1 ^ 0x1BD11BDAu;
  u32 x0 = c0 + k0, x1 = c1 + k1;
#define TF_R(r) { x0 += x1; x1 = ((x1 << (r)) | (x1 >> (32 - (r)))); x1 ^= x0; }
  TF_R(13) TF_R(15) TF_R(26) TF_R(6)
  x0 += k1; x1 += ks2 + 1u;
  TF_R(17) TF_R(29) TF_R(16) TF_R(24)
  x0 += ks2; x1 += k0 + 2u;
  TF_R(13) TF_R(15) TF_R(26) TF_R(6)
  x0 += k0; x1 += k1 + 3u;
  TF_R(17) TF_R(29) TF_R(16) TF_R(24)
  x0 += k1; x1 += ks2 + 4u;
  TF_R(13) TF_R(15) TF_R(26) TF_R(6)
  x0 += ks2; x1 += k0 + 5u;
#undef TF_R
  o0 = x0; o1 = x1;
}

__device__ inline u32 rbits32(u32 k0, u32 k1, u32 i) {
  u32 a, b;
  tf2x32(k0, k1, 0u, i, a, b);
  return a ^ b;
}

__device__ inline float u01f(u32 bits) {
  return __uint_as_float(0x3f800000u | (bits >> 9)) - 1.0f;
}

// f64-log gumbel: argmax-critical path only (bit-stable vs CPU libm)
__device__ inline float gumbel_at(u32 k0, u32 k1, u32 i) {
  float f = u01f(rbits32(k0, k1, i));
  float u = fmaxf(1e-20f, f + 1e-20f);
  float l1 = (float)log((double)u);
  float l2 = (float)log((double)(-l1));
  return -l2;
}

// fast f32 gumbel: continuous-output paths (y1 softmax)
__device__ inline float gumbel_f32(u32 k0, u32 k1, u32 i) {
  float f = u01f(rbits32(k0, k1, i));
  float u = fmaxf(1e-20f, f + 1e-20f);
  float l1 = __logf(u);
  return -__logf(-l1);
}

// XLA f32 ErfInv (Giles polynomial)
__device__ inline float erfinv32(float x) {
  float w = -log1pf(-x * x);
  float p;
  if (w < 5.0f) {
    w -= 2.5f;
    p = 2.81022636e-08f;
    p = fmaf(p, w, 3.43273939e-07f);
    p = fmaf(p, w, -3.5233877e-06f);
    p = fmaf(p, w, -4.39150654e-06f);
    p = fmaf(p, w, 0.00021858087f);
    p = fmaf(p, w, -0.00125372503f);
    p = fmaf(p, w, -0.00417768164f);
    p = fmaf(p, w, 0.246640727f);
    p = fmaf(p, w, 1.50140941f);
  } else {
    w = sqrtf(w) - 3.0f;
    p = -0.000200214257f;
    p = fmaf(p, w, 0.000100950558f);
    p = fmaf(p, w, 0.00134934322f);
    p = fmaf(p, w, -0.00367342844f);
    p = fmaf(p, w, 0.00573950773f);
    p = fmaf(p, w, -0.0076224613f);
    p = fmaf(p, w, 0.00943887047f);
    p = fmaf(p, w, 1.00167406f);
    p = fmaf(p, w, 2.83297682f);
  }
  return p * x;
}

__device__ inline unsigned short f2bf(float f) {
  u32 u = __float_as_uint(f);
  u32 r = (u + 0x7FFFu + ((u >> 16) & 1u)) >> 16;
  return (unsigned short)r;
}

// tile-packed B layout for the LSE MFMA kernels:
// element (col, k) -> tile = col>>4, lane = (col&15) | (((k>>3)&3)<<4),
// dst = tile*4096 + (k>>5)*512 + lane*8 + (k&7)
// => per 16-col step, a wave's 8 loads are each a contiguous 1KB burst
//    (lane*16B, kf*1024B) -- no TA address divergence (R8 diag: 81cyc/instr).
__device__ inline size_t packB(int col, int k0) {
  int lane = (col & 15) | (((k0 >> 3) & 3) << 4);
  return ((size_t)(col >> 4)) * 4096 + ((size_t)(k0 >> 5) << 9) + lane * 8 + (k0 & 7);
}

// ---------------- queue_k raw sumsq (for sk) ----------------
__global__ __launch_bounds__(256)
void k_sumsq(const float* __restrict__ x, int n, float* __restrict__ partial) {
  __shared__ float sm[256];
  float s = 0.0f;
  for (int i = blockIdx.x * 256 + threadIdx.x; i < n; i += gridDim.x * 256) {
    float v = x[i]; s = fmaf(v, v, s);
  }
  sm[threadIdx.x] = s; __syncthreads();
  for (int off = 128; off > 0; off >>= 1) {
    if (threadIdx.x < off) sm[threadIdx.x] += sm[threadIdx.x + off];
    __syncthreads();
  }
  if (threadIdx.x == 0) partial[blockIdx.x] = sm[0];
}

// ---------------- queue_n -> tile-packed bf16 + sumsq partials (fused) ----------------
__global__ __launch_bounds__(256)
void k_prep_n(const float* __restrict__ src, unsigned short* __restrict__ dst,
              float* __restrict__ partial) {
  __shared__ float sm[256];
  int tid = threadIdx.x;
  float s = 0.0f;
  const int n = LL * DD;
  for (int i = (blockIdx.x * 256 + tid) * 4; i < n; i += 256 * 256 * 4) {
    float4 v = *(const float4*)(src + i);
    s = fmaf(v.x, v.x, s); s = fmaf(v.y, v.y, s);
    s = fmaf(v.z, v.z, s); s = fmaf(v.w, v.w, s);
    ushort2 a, b;
    a.x = f2bf(v.x); a.y = f2bf(v.y);
    b.x = f2bf(v.z); b.y = f2bf(v.w);
    size_t d = packB(i >> 8, i & 255);
    *(ushort2*)(dst + d) = a;
    *(ushort2*)(dst + d + 2) = b;
  }
  sm[tid] = s; __syncthreads();
  for (int off = 128; off > 0; off >>= 1) {
    if (tid < off) sm[tid] += sm[tid + off];
    __syncthreads();
  }
  if (tid == 0) partial[blockIdx.x] = sm[0];
}

// ---------------- queue = 2*l2n(qk) + 0.1*normal -> tile-packed bf16 + sumsq ----------------
__global__ __launch_bounds__(256)
void k_queue_fused(const float* __restrict__ qk_in, const float* __restrict__ partK,
                   unsigned short* __restrict__ dst, float* __restrict__ partial,
                   u32 kqa, u32 kqb) {
  __shared__ float sm[256];
  int tid = threadIdx.x;
  sm[tid] = partK[tid]; __syncthreads();
  for (int off = 128; off > 0; off >>= 1) {
    if (tid < off) sm[tid] += sm[tid + off];
    __syncthreads();
  }
  float sk = (float)(1.0 / sqrt((double)fmaxf(sm[0], 1e-12f)));
  __syncthreads();

  int i0 = (blockIdx.x * 256 + tid) * 4;
  float4 v = *(const float4*)(qk_in + i0);
  float vin[4] = {v.x, v.y, v.z, v.w};
  unsigned short h[4];
  float s = 0.0f;
  const float lo = -0.99999994f;
#pragma unroll
  for (int e = 0; e < 4; e++) {
    float qk = vin[e] * sk;
    float f = u01f(rbits32(kqa, kqb, (u32)(i0 + e)));
    float u = fmaxf(lo, f * 2.0f + lo);
    float nv = 1.41421354f * erfinv32(u);
    float t = qk + 0.1f * nv;
    float val = t + qk;
    s = fmaf(val, val, s);
    h[e] = f2bf(val);
  }
  ushort2 a, b;
  a.x = h[0]; a.y = h[1]; b.x = h[2]; b.y = h[3];
  size_t d = packB(i0 >> 8, i0 & 255);
  *(ushort2*)(dst + d) = a;
  *(ushort2*)(dst + d + 2) = b;

  sm[tid] = s; __syncthreads();
  for (int off = 128; off > 0; off >>= 1) {
    if (tid < off) sm[tid] += sm[tid + off];
    __syncthreads();
  }
  if (tid == 0) partial[blockIdx.x] = sm[0];
}

// ---------------- f32 GEMMs: 64x64 tile, 4x4 register tile ----------------
__global__ __launch_bounds__(256)
void k_gemm_nt64(const float* __restrict__ A, const float* __restrict__ Bm,
                 float* __restrict__ C, int N) {
  __shared__ float As[16][68], Bs[16][68];
  int tid = threadIdx.x;
  int tx = tid & 15, ty = tid >> 4;
  int rowBase = blockIdx.y * 64, colBase = blockIdx.x * 64;
  float c[4][4] = {};
  for (int kt = 0; kt < 256; kt += 16) {
#pragma unroll
    for (int q = 0; q < 4; q++) {
      int idx = tid + 256 * q;
      int kkx = idx & 15, rr = idx >> 4;
      As[kkx][rr] = A[(size_t)(rowBase + rr) * 256 + kt + kkx];
      Bs[kkx][rr] = Bm[(size_t)(colBase + rr) * 256 + kt + kkx];
    }
    __syncthreads();
#pragma unroll
    for (int kx = 0; kx < 16; kx++) {
      float4 a4 = *(const float4*)&As[kx][ty * 4];
      float4 b4 = *(const float4*)&Bs[kx][tx * 4];
      float av[4] = {a4.x, a4.y, a4.z, a4.w};
      float bv[4] = {b4.x, b4.y, b4.z, b4.w};
#pragma unroll
      for (int r = 0; r < 4; r++)
#pragma unroll
        for (int q = 0; q < 4; q++)
          c[r][q] = fmaf(av[r], bv[q], c[r][q]);
    }
    __syncthreads();
  }
#pragma unroll
  for (int r = 0; r < 4; r++)
#pragma unroll
    for (int q = 0; q < 4; q++)
      C[(size_t)(rowBase + ty * 4 + r) * N + colBase + tx * 4 + q] = c[r][q];
}

// C[M x N] = A[M x K] * Bm[K x N]; grid (N/64, M/64, S). Optional sumsq partials.
__global__ __launch_bounds__(256)
void k_gemm_nn64(const float* __restrict__ A, const float* __restrict__ Bm,
                 float* __restrict__ C, int N, int K, int M, int Kc,
                 float* __restrict__ sqp) {
  __shared__ float As[16][68], Bs[16][68];
  __shared__ float sq[256];
  int tid = threadIdx.x;
  int tx = tid & 15, ty = tid >> 4;
  int rowBase = blockIdx.y * 64, colBase = blockIdx.x * 64;
  int k0 = blockIdx.z * Kc;
  float c[4][4] = {};
  for (int kt = k0; kt < k0 + Kc; kt += 16) {
#pragma unroll
    for (int q = 0; q < 4; q++) {
      int idx = tid + 256 * q;
      int kkx = idx & 15, rr = idx >> 4;
      As[kkx][rr] = A[(size_t)(rowBase + rr) * K + kt + kkx];
      int kk = (tid >> 6) * 4 + q;
      int jj = tid & 63;
      Bs[kk][jj] = Bm[(size_t)(kt + kk) * N + colBase + jj];
    }
    __syncthreads();
#pragma unroll
    for (int kx = 0; kx < 16; kx++) {
      float4 a4 = *(const float4*)&As[kx][ty * 4];
      float4 b4 = *(const float4*)&Bs[kx][tx * 4];
      float av[4] = {a4.x, a4.y, a4.z, a4.w};
      float bv[4] = {b4.x, b4.y, b4.z, b4.w};
#pragma unroll
      for (int r = 0; r < 4; r++)
#pragma unroll
        for (int q = 0; q < 4; q++)
          c[r][q] = fmaf(av[r], bv[q], c[r][q]);
    }
    __syncthreads();
  }
  float* dst = C + (size_t)blockIdx.z * M * N;
#pragma unroll
  for (int r = 0; r < 4; r++)
#pragma unroll
    for (int q = 0; q < 4; q++)
      dst[(size_t)(rowBase + ty * 4 + r) * N + colBase + tx * 4 + q] = c[r][q];
  if (sqp != nullptr) {
    float ls = 0.0f;
#pragma unroll
    for (int r = 0; r < 4; r++)
#pragma unroll
      for (int q = 0; q < 4; q++) ls = fmaf(c[r][q], c[r][q], ls);
    sq[tid] = ls; __syncthreads();
    for (int off = 128; off > 0; off >>= 1) {
      if (tid < off) sq[tid] += sq[tid + off];
      __syncthreads();
    }
    if (tid == 0) sqp[blockIdx.y * gridDim.x + blockIdx.x] = sq[0];
  }
}

// sum split-K partials, divide by row-sum, emit sumsq partials
__global__ __launch_bounds__(256)
void k_reduce_div(const float* __restrict__ Cp, int S, int MN,
                  const float* __restrict__ rs, float* __restrict__ out,
                  float* __restrict__ sqp) {
  __shared__ float sq[256];
  int tid = threadIdx.x;
  int i = blockIdx.x * 256 + tid;
  float s = 0.0f;
  for (int t = 0; t < S; t++) s += Cp[(size_t)t * MN + i];
  float v = s / (rs[i >> 8] + 1e-8f);
  out[i] = v;
  sq[tid] = v * v; __syncthreads();
  for (int off = 128; off > 0; off >>= 1) {
    if (tid < off) sq[tid] += sq[tid + off];
    __syncthreads();
  }
  if (tid == 0) sqp[blockIdx.x] = sq[0];
}

// reduce sumsq partials -> rsqrt factor; scale in place; optional bf16 out (linear layout)
__global__ __launch_bounds__(256)
void k_scale_cvt(float* __restrict__ data, unsigned short* __restrict__ dstBf,
                 const float* __restrict__ sqp, int np, int n) {
  __shared__ float sm[256];
  int tid = threadIdx.x;
  float a = 0.0f;
  for (int i = tid; i < np; i += 256) a += sqp[i];
  sm[tid] = a; __syncthreads();
  for (int off = 128; off > 0; off >>= 1) {
    if (tid < off) sm[tid] += sm[tid + off];
    __syncthreads();
  }
  float f = (float)(1.0 / sqrt((double)fmaxf(sm[0], 1e-12f)));
  int i = (blockIdx.x * 256 + tid) * 4;
  if (i < n) {
    float4 v = *(const float4*)(data + i);
    v.x *= f; v.y *= f; v.z *= f; v.w *= f;
    *(float4*)(data + i) = v;
    if (dstBf != nullptr) {
      ushort2 p, q;
      p.x = f2bf(v.x); p.y = f2bf(v.y);
      q.x = f2bf(v.z); q.y = f2bf(v.w);
      *(ushort2*)(dstBf + i) = p;
      *(ushort2*)(dstBf + i + 2) = q;
    }
  }
}

// ---------------- softmax(y1) + hard argmax(y2), wave-shuffle reductions ----------------
__global__ __launch_bounds__(256)
void k_softmax_assign(const float* __restrict__ knT, float* __restrict__ Y,
                      float* __restrict__ assignOut,
                      u32 g1a, u32 g1b, u32 g2a, u32 g2b) {
  __shared__ float smA[4], smS[4], smM2[4], smS2[4], smV[4];
  __shared__ int smI[4];
  int b = blockIdx.x, tid = threadIdx.x;
  int lane = tid & 63, wid = tid >> 6;
  int i0 = b * KK + tid, i1 = i0 + 256;
  float x0 = knT[i0], x1 = knT[i1];

  // y1 path: fast f32 gumbels (feeds only continuous outputs)
  float z0 = x0 + gumbel_f32(g1a, g1b, (u32)i0);
  float z1 = x1 + gumbel_f32(g1a, g1b, (u32)i1);
  float wm = fmaxf(z0, z1);
#pragma unroll
  for (int off = 1; off < 64; off <<= 1) wm = fmaxf(wm, __shfl_xor(wm, off, 64));
  if (lane == 0) smA[wid] = wm;
  __syncthreads();
  float m = fmaxf(fmaxf(smA[0], smA[1]), fmaxf(smA[2], smA[3]));
  float e0 = expf(z0 - m), e1 = expf(z1 - m);
  float ws = e0 + e1;
#pragma unroll
  for (int off = 1; off < 64; off <<= 1) ws += __shfl_xor(ws, off, 64);
  if (lane == 0) smS[wid] = ws;
  __syncthreads();
  float s = (smS[0] + smS[1]) + (smS[2] + smS[3]);
  Y[i0] = e0 / s;
  Y[i1] = e1 / s;

  if (assignOut != nullptr) {
    // argmax path: f64-log gumbels, bit-identical to prior passing rounds
    float w0 = x0 + gumbel_at(g2a, g2b, (u32)i0);
    float w1 = x1 + gumbel_at(g2a, g2b, (u32)i1);
    float wm2 = fmaxf(w0, w1);
#pragma unroll
    for (int off = 1; off < 64; off <<= 1) wm2 = fmaxf(wm2, __shfl_xor(wm2, off, 64));
    if (lane == 0) smM2[wid] = wm2;
    __syncthreads();
    float m2 = fmaxf(fmaxf(smM2[0], smM2[1]), fmaxf(smM2[2], smM2[3]));
    float f0 = expf(w0 - m2), f1 = expf(w1 - m2);
    float ws2 = f0 + f1;
#pragma unroll
    for (int off = 1; off < 64; off <<= 1) ws2 += __shfl_xor(ws2, off, 64);
    if (lane == 0) smS2[wid] = ws2;
    __syncthreads();
    float s2 = (smS2[0] + smS2[1]) + (smS2[2] + smS2[3]);
    float y0 = f0 / s2, y1v = f1 / s2;
    float bv; int bi;
    if (y1v > y0) { bv = y1v; bi = tid + 256; } else { bv = y0; bi = tid; }
#pragma unroll
    for (int off = 1; off < 64; off <<= 1) {
      float ov = __shfl_xor(bv, off, 64);
      int oi = __shfl_xor(bi, off, 64);
      if (ov > bv || (ov == bv && oi < bi)) { bv = ov; bi = oi; }
    }
    if (lane == 0) { smV[wid] = bv; smI[wid] = bi; }
    __syncthreads();
    if (tid == 0) {
      float cv = smV[0]; int ci = smI[0];
#pragma unroll
      for (int t = 1; t < 4; t++) {
        if (smV[t] > cv || (smV[t] == cv && smI[t] < ci)) { cv = smV[t]; ci = smI[t]; }
      }
      assignOut[b] = (float)ci;
    }
  }
}

// ---------------- stochastic binary threshold + fused row-sum ----------------
__global__ __launch_bounds__(256)
void k_binary(const float* __restrict__ knT, float* __restrict__ BIN,
              float* __restrict__ rs, u32 k3a, u32 k3b) {
  __shared__ float sm[256];
  int tid = threadIdx.x;
  int i = blockIdx.x * 256 + tid;
  int k = i >> 12, b = i & 4095;
  float x = knT[b * KK + k];
  float prob = (float)(1.0 / (1.0 + exp(-(double)x)));
  float eps = u01f(rbits32(k3a, k3b, (u32)i));
  float bin = (prob > eps) ? 1.0f : 0.0f;
  BIN[i] = bin;
  sm[tid] = bin; __syncthreads();
  for (int off = 128; off > 0; off >>= 1) {
    if (tid < off) sm[tid] += sm[tid + off];
    __syncthreads();
  }
  if (tid == 0) atomicAdd(rs + k, sm[0]);
}

// ---------------- positives: 4 rows/block, wave-shuffle ----------------
__global__ __launch_bounds__(256)
void k_rowdot(const float* __restrict__ A, const float* __restrict__ Bv,
              float* __restrict__ outv) {
  int wave = threadIdx.x >> 6, lane = threadIdx.x & 63;
  int r = blockIdx.x * 4 + wave;
  float4 a = *(const float4*)(A + (size_t)r * 256 + lane * 4);
  float4 b = *(const float4*)(Bv + (size_t)r * 256 + lane * 4);
  float s = a.x * b.x + a.y * b.y + a.z * b.z + a.w * b.w;
#pragma unroll
  for (int off = 1; off < 64; off <<= 1) s += __shfl_xor(s, off, 64);
  if (lane == 0) outv[r] = s;
}

// ---------------- fused bf16-MFMA GEMM + sum-exp, tile-packed B ----------------
// |logits| < 0.01 (globally-l2-normalized operands) -> sum-exp needs no max.
// grid (M/256, nsplit), 4 waves x 64 rows. B is tile-packed: per 16-col step,
// 8 loads of contiguous 1KB bursts (lane*16B + kf*1024B). ps layout: [nsplit][M].
__global__ __launch_bounds__(256)
void k_lse_mfma2(const unsigned short* __restrict__ Qb, const unsigned short* __restrict__ Nbp,
                 const float* __restrict__ sqp, int np, int Lper, int M,
                 float* __restrict__ ps) {
  __shared__ float red[256];
  int tid = threadIdx.x;
  float a = 0.0f;
  for (int i = tid; i < np; i += 256) a += sqp[i];
  red[tid] = a; __syncthreads();
  for (int off = 128; off > 0; off >>= 1) {
    if (tid < off) red[tid] += red[tid + off];
    __syncthreads();
  }
  float sr = (float)(1.0 / sqrt((double)fmaxf(red[0], 1e-12f)));
  float lsc = sr / 0.07f;

  int wave = tid >> 6, lane = tid & 63;
  int rowBase = blockIdx.x * 256 + wave * 64;
  int tile0 = blockIdx.y * (Lper >> 4);
  int lr = lane & 15;
  int lk = (lane >> 4) * 8;

  short8 afr[4][8];
#pragma unroll
  for (int ts = 0; ts < 4; ts++)
#pragma unroll
    for (int kf = 0; kf < 8; kf++)
      afr[ts][kf] = *(const short8*)(Qb + (size_t)(rowBase + ts * 16 + lr) * 256 + kf * 32 + lk);

  float s[4][4];
#pragma unroll
  for (int ts = 0; ts < 4; ts++)
#pragma unroll
    for (int r = 0; r < 4; r++) s[ts][r] = 0.0f;

  int ntiles = Lper >> 4;
  for (int jt = 0; jt < ntiles; jt++) {
    const unsigned short* bbase = Nbp + (((size_t)(tile0 + jt)) << 12) + lane * 8;
    short8 bfr[8];
#pragma unroll
    for (int kf = 0; kf < 8; kf++) bfr[kf] = *(const short8*)(bbase + (kf << 9));
#pragma unroll
    for (int ts = 0; ts < 4; ts++) {
      f32x4 acc = {0.f, 0.f, 0.f, 0.f};
#pragma unroll
      for (int kf = 0; kf < 8; kf++)
        acc = __builtin_amdgcn_mfma_f32_16x16x32_bf16(afr[ts][kf], bfr[kf], acc, 0, 0, 0);
#pragma unroll
      for (int r = 0; r < 4; r++)
        s[ts][r] += __expf(acc[r] * lsc);
    }
  }
#pragma unroll
  for (int off = 1; off < 16; off <<= 1)
#pragma unroll
    for (int ts = 0; ts < 4; ts++)
#pragma unroll
      for (int r = 0; r < 4; r++)
        s[ts][r] += __shfl_xor(s[ts][r], off, 64);
  if (lr == 0) {
    int rg = (lane >> 4) * 4;
#pragma unroll
    for (int ts = 0; ts < 4; ts++)
#pragma unroll
      for (int r = 0; r < 4; r++)
        ps[(size_t)blockIdx.y * M + rowBase + ts * 16 + rg + r] = s[ts][r];
  }
}

// partial row-LSE sums: grid nb blocks, one row per thread (M = nb*256)
__global__ __launch_bounds__(256)
void k_lse_partial(const float* __restrict__ ps, int nsplit,
                   const float* __restrict__ lpos, int M, float* __restrict__ partial) {
  __shared__ float sm[256];
  int tid = threadIdx.x;
  int row = blockIdx.x * 256 + tid;
  float s = 0.0f;
  for (int t = 0; t < nsplit; t++) s += ps[(size_t)t * M + row];
  float z0 = lpos[row] / 0.07f;
  s += expf(z0);
  float acc = logf(s) - z0;
  sm[tid] = acc; __syncthreads();
  for (int off = 128; off > 0; off >>= 1) {
    if (tid < off) sm[tid] += sm[tid + off];
    __syncthreads();
  }
  if (tid == 0) partial[blockIdx.x] = sm[0];
}

__global__ void k_loss_merge(const float* __restrict__ PN, int nN, int MN,
                             const float* __restrict__ PK, int nK, int MK,
                             float* __restrict__ outLoss) {
  if (threadIdx.x == 0) {
    float a = 0.0f, b = 0.0f;
    for (int i = 0; i < nN; i++) a += PN[i];
    for (int i = 0; i < nK; i++) b += PK[i];
    outLoss[0] = a / (float)MN + b / (float)MK;
  }
}

// ---------------- launch ----------------
extern "C" void kernel_launch(void* const* d_in, const int* in_sizes, int n_in,
                              void* d_out, int out_size, void* d_ws, size_t ws_size,
                              hipStream_t stream) {
  const float* feat[2] = {(const float*)d_in[0], (const float*)d_in[1]};
  const float* ctx[2]  = {(const float*)d_in[2], (const float*)d_in[3]};
  const float* queue_n = (const float*)d_in[4];
  const float* queue_k = (const float*)d_in[5];

  float* W = (float*)d_ws;
  size_t o = 0;
  float* T     = W + o; o += (size_t)BB * KK;   // 2M floats
  float* Yb    = W + o; o += (size_t)BB * KK;   // 2M (also split-K partials CP)
  float* BIN   = W + o; o += (size_t)KK * BB;   // 2M
  float* AGGN1 = W + o; o += (size_t)BB * DD;   // 1M
  float* AGGK1 = W + o; o += (size_t)KK * DD;   // 128K
  float* FREE  = W + o; o += (size_t)QQ * DD;   // 2M floats repurposed region
  float* RS    = W + o; o += KK;
  float* LPOSN = W + o; o += BB;
  float* LPOSK = W + o; o += KK;
  float* PNp   = W + o; o += 32;
  float* PKp   = W + o; o += 32;

  // QNb/QUb (tile-packed) overlay the dead T/Yb/BIN region
  unsigned short* QNb  = (unsigned short*)T;          // 8.4M shorts (16.8MB)
  unsigned short* QUb  = QNb + (size_t)LL * DD;       // 2.1M shorts (4.2MB)
  // FREE region (8MB): bf16 agg operands (linear) + PSBUF + partial buffers
  unsigned short* AGNb = (unsigned short*)FREE;                    // 1.05M shorts
  unsigned short* AGKb = AGNb + (size_t)BB * DD;                   // 131K shorts
  float* PSBUF  = (float*)(AGKb + (size_t)KK * DD);                // up to 262144 floats
  float* PART_N = PSBUF + 64 * BB;                                 // 256
  float* PART_K = PART_N + 256;                                    // 256
  float* PART_Q = PART_K + 256;                                    // 2048
  float* SQPN   = PART_Q + 2048;                                   // 256
  float* SQPK   = SQPN + 256;                                      // 512

  float* out = (float*)d_out;
  float* outAssign = out;
  float* outAggn2  = out + BB;
  float* outAggk2  = out + BB + (size_t)BB * DD;
  float* outLoss   = out + BB + (size_t)BB * DD + (size_t)KK * DD;

  u32 kq0, kq1, kc[2][2];
  tf2x32(0u, 42u, 0u, 0u, kq0, kq1);
  tf2x32(0u, 42u, 0u, 1u, kc[0][0], kc[0][1]);
  tf2x32(0u, 42u, 0u, 2u, kc[1][0], kc[1][1]);
  u32 sub[2][3][2];
  for (int br = 0; br < 2; br++)
    for (int t = 0; t < 3; t++)
      tf2x32(kc[br][0], kc[br][1], 0u, (u32)t, sub[br][t][0], sub[br][t][1]);

  // sk partials (queue_k raw)
  k_sumsq<<<256, 256, 0, stream>>>(queue_k, QQ * DD, PART_K);

  for (int br = 0; br < 2; br++) {
    float* aggn = (br == 0) ? AGGN1 : outAggn2;
    float* aggk = (br == 0) ? AGGK1 : outAggk2;
    hipMemsetAsync(RS, 0, KK * sizeof(float), stream);
    k_gemm_nt64<<<dim3(KK / 64, BB / 64), 256, 0, stream>>>(feat[br], ctx[br], T, KK);
    k_softmax_assign<<<BB, 256, 0, stream>>>(T, Yb, br == 0 ? outAssign : nullptr,
        sub[br][0][0], sub[br][0][1], sub[br][1][0], sub[br][1][1]);
    k_binary<<<(KK * BB) / 256, 256, 0, stream>>>(T, BIN, RS, sub[br][2][0], sub[br][2][1]);
    k_gemm_nn64<<<dim3(DD / 64, BB / 64, 1), 256, 0, stream>>>(Yb, ctx[br], aggn, DD, KK, BB, KK, SQPN);
    k_gemm_nn64<<<dim3(DD / 64, KK / 64, 8), 256, 0, stream>>>(BIN, feat[br], Yb, DD, BB, KK, 512, nullptr);
    k_reduce_div<<<(KK * DD) / 256, 256, 0, stream>>>(Yb, 8, KK * DD, RS, aggk, SQPK);
    k_scale_cvt<<<(BB * DD) / 1024, 256, 0, stream>>>(aggn, br == 0 ? AGNb : nullptr, SQPN, 256, BB * DD);
    k_scale_cvt<<<(KK * DD) / 1024, 256, 0, stream>>>(aggk, br == 0 ? AGKb : nullptr, SQPK, 512, KK * DD);
  }

  // loss operand prep (T/Yb/BIN dead from here); writes tile-packed bf16
  k_prep_n<<<256, 256, 0, stream>>>(queue_n, QNb, PART_N);
  k_queue_fused<<<(QQ * DD) / 1024, 256, 0, stream>>>(queue_k, PART_K, QUb, PART_Q, kq0, kq1);

  // positives
  k_rowdot<<<BB / 4, 256, 0, stream>>>(AGGN1, outAggn2, LPOSN);
  k_rowdot<<<KK / 4, 256, 0, stream>>>(AGGK1, outAggk2, LPOSK);

  // loss_n: nsplit=64, Lper=512
  k_lse_mfma2<<<dim3(BB / 256, 64), 256, 0, stream>>>(AGNb, QNb, PART_N, 256, LL / 64, BB, PSBUF);
  k_lse_partial<<<BB / 256, 256, 0, stream>>>(PSBUF, 64, LPOSN, BB, PNp);
  // loss_k: nsplit=128, Lper=64
  k_lse_mfma2<<<dim3(KK / 256, 128), 256, 0, stream>>>(AGKb, QUb, PART_Q, 2048, QQ / 128, KK, PSBUF);
  k_lse_partial<<<KK / 256, 256, 0, stream>>>(PSBUF, 128, LPOSK, KK, PKp);
  k_loss_merge<<<1, 64, 0, stream>>>(PNp, BB / 256, BB, PKp, KK / 256, KK, outLoss);
}

// Round 10
// 357.744 us; speedup vs baseline: 2.0177x; 1.3445x over previous
//
#include <hip/hip_runtime.h>
#include <stdint.h>
#include <math.h>

typedef unsigned int u32;

#define BB 4096
#define DD 256
#define KK 512
#define LL 32768
#define QQ 8192

// ---------------- Threefry2x32 (JAX-exact, 20 rounds) ----------------
__host__ __device__ inline void tf2x32(u32 k0, u32 k1, u32 c0, u32 c1, u32& o0, u32& o1) {
  u32 ks2 = k0 ^ k1 ^ 0x1BD11BDAu;
  u32 x0 = c0 + k0, x1 = c1 + k1;
#define TF_R(r) { x0 += x1; x1 = ((x1 << (r)) | (x1 >> (32 - (r)))); x1 ^= x0; }
  TF_R(13) TF_R(15) TF_R(26) TF_R(6)
  x0 += k1; x1 += ks2 + 1u;
  TF_R(17) TF_R(29) TF_R(16) TF_R(24)
  x0 += ks2; x1 += k0 + 2u;
  TF_R(13) TF_R(15) TF_R(26) TF_R(6)
  x0 += k0; x1 += k1 + 3u;
  TF_R(17) TF_R(29) TF_R(16) TF_R(24)
  x0 += k1; x1 += ks2 + 4u;
  TF_R(13) TF_R(15) TF_R(26) TF_R(6)
  x0 += ks2; x1 += k0 + 5u;
#undef TF_R
  o0 = x0; o1 = x1;
}

__device__ inline u32 rbits32(u32 k0, u32 k1, u32 i) {
  u32 a, b;
  tf2x32(k0, k1, 0u, i, a, b);
  return a ^ b;
}

__device__ inline float u01f(u32 bits) {
  return __uint_as_float(0x3f800000u | (bits >> 9)) - 1.0f;
}

// f64-log gumbel: argmax-critical path only (bit-stable vs CPU libm)
__device__ inline float gumbel_at(u32 k0, u32 k1, u32 i) {
  float f = u01f(rbits32(k0, k1, i));
  float u = fmaxf(1e-20f, f + 1e-20f);
  float l1 = (float)log((double)u);
  float l2 = (float)log((double)(-l1));
  return -l2;
}

// fast f32 gumbel: continuous-output paths (y1 softmax)
__device__ inline float gumbel_f32(u32 k0, u32 k1, u32 i) {
  float f = u01f(rbits32(k0, k1, i));
  float u = fmaxf(1e-20f, f + 1e-20f);
  float l1 = __logf(u);
  return -__logf(-l1);
}

// XLA f32 ErfInv (Giles polynomial)
__device__ inline float erfinv32(float x) {
  float w = -log1pf(-x * x);
  float p;
  if (w < 5.0f) {
    w -= 2.5f;
    p = 2.81022636e-08f;
    p = fmaf(p, w, 3.43273939e-07f);
    p = fmaf(p, w, -3.5233877e-06f);
    p = fmaf(p, w, -4.39150654e-06f);
    p = fmaf(p, w, 0.00021858087f);
    p = fmaf(p, w, -0.00125372503f);
    p = fmaf(p, w, -0.00417768164f);
    p = fmaf(p, w, 0.246640727f);
    p = fmaf(p, w, 1.50140941f);
  } else {
    w = sqrtf(w) - 3.0f;
    p = -0.000200214257f;
    p = fmaf(p, w, 0.000100950558f);
    p = fmaf(p, w, 0.00134934322f);
    p = fmaf(p, w, -0.00367342844f);
    p = fmaf(p, w, 0.00573950773f);
    p = fmaf(p, w, -0.0076224613f);
    p = fmaf(p, w, 0.00943887047f);
    p = fmaf(p, w, 1.00167406f);
    p = fmaf(p, w, 2.83297682f);
  }
  return p * x;
}

// ---------------- queue_k raw sumsq (for sk) ----------------
__global__ __launch_bounds__(256)
void k_sumsq(const float* __restrict__ x, int n, float* __restrict__ partial) {
  __shared__ float sm[256];
  float s = 0.0f;
  for (int i = blockIdx.x * 256 + threadIdx.x; i < n; i += gridDim.x * 256) {
    float v = x[i]; s = fmaf(v, v, s);
  }
  sm[threadIdx.x] = s; __syncthreads();
  for (int off = 128; off > 0; off >>= 1) {
    if (threadIdx.x < off) sm[threadIdx.x] += sm[threadIdx.x + off];
    __syncthreads();
  }
  if (threadIdx.x == 0) partial[blockIdx.x] = sm[0];
}

// ---------------- queue_n stats: column sums + sumsq partials ----------------
// grid 256 blocks, block b handles rows [b*128, (b+1)*128); thread d = column.
__global__ __launch_bounds__(256)
void k_stats_n(const float* __restrict__ src, float* __restrict__ colpart,
               float* __restrict__ sqpart) {
  __shared__ float sm[256];
  int d = threadIdx.x, b = blockIdx.x;
  float cs = 0.0f, ss = 0.0f;
  for (int j = b * 128; j < (b + 1) * 128; j++) {
    float v = src[(size_t)j * 256 + d];
    cs += v; ss = fmaf(v, v, ss);
  }
  colpart[b * 256 + d] = cs;
  sm[d] = ss; __syncthreads();
  for (int off = 128; off > 0; off >>= 1) {
    if (d < off) sm[d] += sm[d + off];
    __syncthreads();
  }
  if (d == 0) sqpart[b] = sm[0];
}

// ---------------- queue stats: construct QUEUE on the fly (never materialized),
// accumulate column sums + sumsq. grid 256 blocks, 32 rows each. ----------------
__global__ __launch_bounds__(256)
void k_stats_queue(const float* __restrict__ qk_in, const float* __restrict__ partK,
                   float* __restrict__ colpart, float* __restrict__ sqpart,
                   u32 kqa, u32 kqb) {
  __shared__ float sm[256];
  int d = threadIdx.x, b = blockIdx.x;
  sm[d] = partK[d]; __syncthreads();
  for (int off = 128; off > 0; off >>= 1) {
    if (d < off) sm[d] += sm[d + off];
    __syncthreads();
  }
  float sk = (float)(1.0 / sqrt((double)fmaxf(sm[0], 1e-12f)));
  __syncthreads();

  const float lo = -0.99999994f;
  float cs = 0.0f, ss = 0.0f;
  for (int j = b * 32; j < (b + 1) * 32; j++) {
    int i = j * 256 + d;
    float qk = qk_in[i] * sk;
    float f = u01f(rbits32(kqa, kqb, (u32)i));
    float u = fmaxf(lo, f * 2.0f + lo);
    float nv = 1.41421354f * erfinv32(u);
    float t = qk + 0.1f * nv;
    float val = t + qk;
    cs += val; ss = fmaf(val, val, ss);
  }
  colpart[b * 256 + d] = cs;
  sm[d] = ss; __syncthreads();
  for (int off = 128; off > 0; off >>= 1) {
    if (d < off) sm[d] += sm[d + off];
    __syncthreads();
  }
  if (d == 0) sqpart[b] = sm[0];
}

// reduce col partials (fixed order, deterministic) + sumsq -> csum, lsc = rsqrt/0.07
__global__ __launch_bounds__(256)
void k_finalize_stats(const float* __restrict__ colpart, const float* __restrict__ sqpart,
                      float* __restrict__ csum, float* __restrict__ lscOut) {
  __shared__ float sm[256];
  int d = threadIdx.x;
  float c = 0.0f;
  for (int b = 0; b < 256; b++) c += colpart[b * 256 + d];
  csum[d] = c;
  sm[d] = sqpart[d]; __syncthreads();
  for (int off = 128; off > 0; off >>= 1) {
    if (d < off) sm[d] += sm[d + off];
    __syncthreads();
  }
  if (d == 0) {
    float sr = (float)(1.0 / sqrt((double)fmaxf(sm[0], 1e-12f)));
    lscOut[0] = sr / 0.07f;
  }
}

// ---------------- f32 GEMMs: 64x64 tile, 4x4 register tile ----------------
__global__ __launch_bounds__(256)
void k_gemm_nt64(const float* __restrict__ A, const float* __restrict__ Bm,
                 float* __restrict__ C, int N) {
  __shared__ float As[16][68], Bs[16][68];
  int tid = threadIdx.x;
  int tx = tid & 15, ty = tid >> 4;
  int rowBase = blockIdx.y * 64, colBase = blockIdx.x * 64;
  float c[4][4] = {};
  for (int kt = 0; kt < 256; kt += 16) {
#pragma unroll
    for (int q = 0; q < 4; q++) {
      int idx = tid + 256 * q;
      int kkx = idx & 15, rr = idx >> 4;
      As[kkx][rr] = A[(size_t)(rowBase + rr) * 256 + kt + kkx];
      Bs[kkx][rr] = Bm[(size_t)(colBase + rr) * 256 + kt + kkx];
    }
    __syncthreads();
#pragma unroll
    for (int kx = 0; kx < 16; kx++) {
      float4 a4 = *(const float4*)&As[kx][ty * 4];
      float4 b4 = *(const float4*)&Bs[kx][tx * 4];
      float av[4] = {a4.x, a4.y, a4.z, a4.w};
      float bv[4] = {b4.x, b4.y, b4.z, b4.w};
#pragma unroll
      for (int r = 0; r < 4; r++)
#pragma unroll
        for (int q = 0; q < 4; q++)
          c[r][q] = fmaf(av[r], bv[q], c[r][q]);
    }
    __syncthreads();
  }
#pragma unroll
  for (int r = 0; r < 4; r++)
#pragma unroll
    for (int q = 0; q < 4; q++)
      C[(size_t)(rowBase + ty * 4 + r) * N + colBase + tx * 4 + q] = c[r][q];
}

// C[M x N] = A[M x K] * Bm[K x N]; grid (N/64, M/64, S). Optional sumsq partials.
__global__ __launch_bounds__(256)
void k_gemm_nn64(const float* __restrict__ A, const float* __restrict__ Bm,
                 float* __restrict__ C, int N, int K, int M, int Kc,
                 float* __restrict__ sqp) {
  __shared__ float As[16][68], Bs[16][68];
  __shared__ float sq[256];
  int tid = threadIdx.x;
  int tx = tid & 15, ty = tid >> 4;
  int rowBase = blockIdx.y * 64, colBase = blockIdx.x * 64;
  int k0 = blockIdx.z * Kc;
  float c[4][4] = {};
  for (int kt = k0; kt < k0 + Kc; kt += 16) {
#pragma unroll
    for (int q = 0; q < 4; q++) {
      int idx = tid + 256 * q;
      int kkx = idx & 15, rr = idx >> 4;
      As[kkx][rr] = A[(size_t)(rowBase + rr) * K + kt + kkx];
      int kk = (tid >> 6) * 4 + q;
      int jj = tid & 63;
      Bs[kk][jj] = Bm[(size_t)(kt + kk) * N + colBase + jj];
    }
    __syncthreads();
#pragma unroll
    for (int kx = 0; kx < 16; kx++) {
      float4 a4 = *(const float4*)&As[kx][ty * 4];
      float4 b4 = *(const float4*)&Bs[kx][tx * 4];
      float av[4] = {a4.x, a4.y, a4.z, a4.w};
      float bv[4] = {b4.x, b4.y, b4.z, b4.w};
#pragma unroll
      for (int r = 0; r < 4; r++)
#pragma unroll
        for (int q = 0; q < 4; q++)
          c[r][q] = fmaf(av[r], bv[q], c[r][q]);
    }
    __syncthreads();
  }
  float* dst = C + (size_t)blockIdx.z * M * N;
#pragma unroll
  for (int r = 0; r < 4; r++)
#pragma unroll
    for (int q = 0; q < 4; q++)
      dst[(size_t)(rowBase + ty * 4 + r) * N + colBase + tx * 4 + q] = c[r][q];
  if (sqp != nullptr) {
    float ls = 0.0f;
#pragma unroll
    for (int r = 0; r < 4; r++)
#pragma unroll
      for (int q = 0; q < 4; q++) ls = fmaf(c[r][q], c[r][q], ls);
    sq[tid] = ls; __syncthreads();
    for (int off = 128; off > 0; off >>= 1) {
      if (tid < off) sq[tid] += sq[tid + off];
      __syncthreads();
    }
    if (tid == 0) sqp[blockIdx.y * gridDim.x + blockIdx.x] = sq[0];
  }
}

// sum split-K partials, divide by row-sum, emit sumsq partials
__global__ __launch_bounds__(256)
void k_reduce_div(const float* __restrict__ Cp, int S, int MN,
                  const float* __restrict__ rs, float* __restrict__ out,
                  float* __restrict__ sqp) {
  __shared__ float sq[256];
  int tid = threadIdx.x;
  int i = blockIdx.x * 256 + tid;
  float s = 0.0f;
  for (int t = 0; t < S; t++) s += Cp[(size_t)t * MN + i];
  float v = s / (rs[i >> 8] + 1e-8f);
  out[i] = v;
  sq[tid] = v * v; __syncthreads();
  for (int off = 128; off > 0; off >>= 1) {
    if (tid < off) sq[tid] += sq[tid + off];
    __syncthreads();
  }
  if (tid == 0) sqp[blockIdx.x] = sq[0];
}

// reduce sumsq partials -> rsqrt factor; scale in place
__global__ __launch_bounds__(256)
void k_scale_cvt(float* __restrict__ data, const float* __restrict__ sqp, int np, int n) {
  __shared__ float sm[256];
  int tid = threadIdx.x;
  float a = 0.0f;
  for (int i = tid; i < np; i += 256) a += sqp[i];
  sm[tid] = a; __syncthreads();
  for (int off = 128; off > 0; off >>= 1) {
    if (tid < off) sm[tid] += sm[tid + off];
    __syncthreads();
  }
  float f = (float)(1.0 / sqrt((double)fmaxf(sm[0], 1e-12f)));
  int i = (blockIdx.x * 256 + tid) * 4;
  if (i < n) {
    float4 v = *(const float4*)(data + i);
    v.x *= f; v.y *= f; v.z *= f; v.w *= f;
    *(float4*)(data + i) = v;
  }
}

// ---------------- softmax(y1) + hard argmax(y2), wave-shuffle reductions ----------------
__global__ __launch_bounds__(256)
void k_softmax_assign(const float* __restrict__ knT, float* __restrict__ Y,
                      float* __restrict__ assignOut,
                      u32 g1a, u32 g1b, u32 g2a, u32 g2b) {
  __shared__ float smA[4], smS[4], smM2[4], smS2[4], smV[4];
  __shared__ int smI[4];
  int b = blockIdx.x, tid = threadIdx.x;
  int lane = tid & 63, wid = tid >> 6;
  int i0 = b * KK + tid, i1 = i0 + 256;
  float x0 = knT[i0], x1 = knT[i1];

  // y1 path: fast f32 gumbels (feeds only continuous outputs)
  float z0 = x0 + gumbel_f32(g1a, g1b, (u32)i0);
  float z1 = x1 + gumbel_f32(g1a, g1b, (u32)i1);
  float wm = fmaxf(z0, z1);
#pragma unroll
  for (int off = 1; off < 64; off <<= 1) wm = fmaxf(wm, __shfl_xor(wm, off, 64));
  if (lane == 0) smA[wid] = wm;
  __syncthreads();
  float m = fmaxf(fmaxf(smA[0], smA[1]), fmaxf(smA[2], smA[3]));
  float e0 = expf(z0 - m), e1 = expf(z1 - m);
  float ws = e0 + e1;
#pragma unroll
  for (int off = 1; off < 64; off <<= 1) ws += __shfl_xor(ws, off, 64);
  if (lane == 0) smS[wid] = ws;
  __syncthreads();
  float s = (smS[0] + smS[1]) + (smS[2] + smS[3]);
  Y[i0] = e0 / s;
  Y[i1] = e1 / s;

  if (assignOut != nullptr) {
    // argmax path: f64-log gumbels, bit-identical to prior passing rounds
    float w0 = x0 + gumbel_at(g2a, g2b, (u32)i0);
    float w1 = x1 + gumbel_at(g2a, g2b, (u32)i1);
    float wm2 = fmaxf(w0, w1);
#pragma unroll
    for (int off = 1; off < 64; off <<= 1) wm2 = fmaxf(wm2, __shfl_xor(wm2, off, 64));
    if (lane == 0) smM2[wid] = wm2;
    __syncthreads();
    float m2 = fmaxf(fmaxf(smM2[0], smM2[1]), fmaxf(smM2[2], smM2[3]));
    float f0 = expf(w0 - m2), f1 = expf(w1 - m2);
    float ws2 = f0 + f1;
#pragma unroll
    for (int off = 1; off < 64; off <<= 1) ws2 += __shfl_xor(ws2, off, 64);
    if (lane == 0) smS2[wid] = ws2;
    __syncthreads();
    float s2 = (smS2[0] + smS2[1]) + (smS2[2] + smS2[3]);
    float y0 = f0 / s2, y1v = f1 / s2;
    float bv; int bi;
    if (y1v > y0) { bv = y1v; bi = tid + 256; } else { bv = y0; bi = tid; }
#pragma unroll
    for (int off = 1; off < 64; off <<= 1) {
      float ov = __shfl_xor(bv, off, 64);
      int oi = __shfl_xor(bi, off, 64);
      if (ov > bv || (ov == bv && oi < bi)) { bv = ov; bi = oi; }
    }
    if (lane == 0) { smV[wid] = bv; smI[wid] = bi; }
    __syncthreads();
    if (tid == 0) {
      float cv = smV[0]; int ci = smI[0];
#pragma unroll
      for (int t = 1; t < 4; t++) {
        if (smV[t] > cv || (smV[t] == cv && smI[t] < ci)) { cv = smV[t]; ci = smI[t]; }
      }
      assignOut[b] = (float)ci;
    }
  }
}

// ---------------- stochastic binary threshold + fused row-sum ----------------
// f32 sigmoid: BIN feeds only continuous outputs (agg_k, loss_k) -- a flip
// perturbs ~0.05% of one row vs 2% threshold; expected flips ~0.4 total.
__global__ __launch_bounds__(256)
void k_binary(const float* __restrict__ knT, float* __restrict__ BIN,
              float* __restrict__ rs, u32 k3a, u32 k3b) {
  __shared__ float sm[256];
  int tid = threadIdx.x;
  int i = blockIdx.x * 256 + tid;
  int k = i >> 12, b = i & 4095;
  float x = knT[b * KK + k];
  float prob = 1.0f / (1.0f + expf(-x));
  float eps = u01f(rbits32(k3a, k3b, (u32)i));
  float bin = (prob > eps) ? 1.0f : 0.0f;
  BIN[i] = bin;
  sm[tid] = bin; __syncthreads();
  for (int off = 128; off > 0; off >>= 1) {
    if (tid < off) sm[tid] += sm[tid + off];
    __syncthreads();
  }
  if (tid == 0) atomicAdd(rs + k, sm[0]);
}

// ---------------- Taylor-collapsed InfoNCE loss ----------------
// S_i = Lc + exp(z0_i) + lsc*(q_i . csum); term = log(S_i) - z0_i.
// Valid: |neg logits| <= ~5e-3 (global l2n), quadratic remainder < 1e-3 abs
// in S (threshold margin >400x). grid M/4, wave w = row bid*4+w.
__global__ __launch_bounds__(256)
void k_loss_row(const float* __restrict__ Q, const float* __restrict__ KP,
                const float* __restrict__ csum, const float* __restrict__ lscp,
                float Lc, float* __restrict__ partial) {
  __shared__ float pt[4];
  int w = threadIdx.x >> 6, l = threadIdx.x & 63;
  int r = blockIdx.x * 4 + w;
  float4 q = *(const float4*)(Q + (size_t)r * 256 + l * 4);
  float4 kp = *(const float4*)(KP + (size_t)r * 256 + l * 4);
  float4 cs = *(const float4*)(csum + l * 4);
  float d1 = q.x * kp.x + q.y * kp.y + q.z * kp.z + q.w * kp.w;
  float d2 = q.x * cs.x + q.y * cs.y + q.z * cs.z + q.w * cs.w;
#pragma unroll
  for (int off = 1; off < 64; off <<= 1) {
    d1 += __shfl_xor(d1, off, 64);
    d2 += __shfl_xor(d2, off, 64);
  }
  if (l == 0) {
    float z0 = d1 / 0.07f;
    double S = (double)Lc + (double)expf(z0) + (double)(lscp[0] * d2);
    pt[w] = (float)(log(S)) - z0;
  }
  __syncthreads();
  if (threadIdx.x == 0) partial[blockIdx.x] = (pt[0] + pt[1]) + (pt[2] + pt[3]);
}

__global__ __launch_bounds__(256)
void k_loss_final(const float* __restrict__ LPN, int nN, float invMN,
                  const float* __restrict__ LPK, int nK, float invMK,
                  float* __restrict__ outLoss) {
  __shared__ float sm[256];
  int tid = threadIdx.x;
  float a = 0.0f;
  for (int i = tid; i < nN; i += 256) a += LPN[i];
  sm[tid] = a; __syncthreads();
  for (int off = 128; off > 0; off >>= 1) {
    if (tid < off) sm[tid] += sm[tid + off];
    __syncthreads();
  }
  float lossN = sm[0] * invMN;
  __syncthreads();
  float b = 0.0f;
  for (int i = tid; i < nK; i += 256) b += LPK[i];
  sm[tid] = b; __syncthreads();
  for (int off = 128; off > 0; off >>= 1) {
    if (tid < off) sm[tid] += sm[tid + off];
    __syncthreads();
  }
  if (tid == 0) outLoss[0] = lossN + sm[0] * invMK;
}

// ---------------- launch ----------------
extern "C" void kernel_launch(void* const* d_in, const int* in_sizes, int n_in,
                              void* d_out, int out_size, void* d_ws, size_t ws_size,
                              hipStream_t stream) {
  const float* feat[2] = {(const float*)d_in[0], (const float*)d_in[1]};
  const float* ctx[2]  = {(const float*)d_in[2], (const float*)d_in[3]};
  const float* queue_n = (const float*)d_in[4];
  const float* queue_k = (const float*)d_in[5];

  float* W = (float*)d_ws;
  size_t o = 0;
  float* T     = W + o; o += (size_t)BB * KK;   // knT (f32-exact, argmax path)
  float* Yb    = W + o; o += (size_t)BB * KK;   // Y; reused as split-K partials
  float* BIN   = W + o; o += (size_t)KK * BB;
  float* AGGN1 = W + o; o += (size_t)BB * DD;
  float* AGGK1 = W + o; o += (size_t)KK * DD;
  float* FREE  = W + o; o += (size_t)QQ * DD;   // scratch region
  float* RS    = W + o; o += KK;

  float* CPN  = FREE;              // 65536 col partials (queue_n)
  float* CPQ  = CPN + 65536;       // 65536 col partials (constructed queue)
  float* SQN2 = CPQ + 65536;       // 256
  float* SQQ2 = SQN2 + 256;        // 256
  float* CSN  = SQQ2 + 256;        // 256
  float* CSQ  = CSN + 256;         // 256
  float* LSCN = CSQ + 256;         // 4
  float* LSCQ = LSCN + 4;          // 4
  float* LPN  = LSCQ + 4;          // 1024
  float* LPK  = LPN + 1024;        // 128
  float* PART_K = LPK + 128;       // 256 (queue_k raw sumsq)
  float* SQPN = PART_K + 256;      // 256
  float* SQPK = SQPN + 256;        // 512

  float* out = (float*)d_out;
  float* outAssign = out;
  float* outAggn2  = out + BB;
  float* outAggk2  = out + BB + (size_t)BB * DD;
  float* outLoss   = out + BB + (size_t)BB * DD + (size_t)KK * DD;

  u32 kq0, kq1, kc[2][2];
  tf2x32(0u, 42u, 0u, 0u, kq0, kq1);
  tf2x32(0u, 42u, 0u, 1u, kc[0][0], kc[0][1]);
  tf2x32(0u, 42u, 0u, 2u, kc[1][0], kc[1][1]);
  u32 sub[2][3][2];
  for (int br = 0; br < 2; br++)
    for (int t = 0; t < 3; t++)
      tf2x32(kc[br][0], kc[br][1], 0u, (u32)t, sub[br][t][0], sub[br][t][1]);

  // queue_k raw sumsq (sk), queue_n stats (csum + sumsq)
  k_sumsq<<<256, 256, 0, stream>>>(queue_k, QQ * DD, PART_K);
  k_stats_n<<<256, 256, 0, stream>>>(queue_n, CPN, SQN2);
  k_finalize_stats<<<1, 256, 0, stream>>>(CPN, SQN2, CSN, LSCN);
  // constructed queue stats (never materialized)
  k_stats_queue<<<256, 256, 0, stream>>>(queue_k, PART_K, CPQ, SQQ2, kq0, kq1);
  k_finalize_stats<<<1, 256, 0, stream>>>(CPQ, SQQ2, CSQ, LSCQ);

  for (int br = 0; br < 2; br++) {
    float* aggn = (br == 0) ? AGGN1 : outAggn2;
    float* aggk = (br == 0) ? AGGK1 : outAggk2;
    hipMemsetAsync(RS, 0, KK * sizeof(float), stream);
    k_gemm_nt64<<<dim3(KK / 64, BB / 64), 256, 0, stream>>>(feat[br], ctx[br], T, KK);
    k_softmax_assign<<<BB, 256, 0, stream>>>(T, Yb, br == 0 ? outAssign : nullptr,
        sub[br][0][0], sub[br][0][1], sub[br][1][0], sub[br][1][1]);
    k_binary<<<(KK * BB) / 256, 256, 0, stream>>>(T, BIN, RS, sub[br][2][0], sub[br][2][1]);
    k_gemm_nn64<<<dim3(DD / 64, BB / 64, 1), 256, 0, stream>>>(Yb, ctx[br], aggn, DD, KK, BB, KK, SQPN);
    k_gemm_nn64<<<dim3(DD / 64, KK / 64, 8), 256, 0, stream>>>(BIN, feat[br], Yb, DD, BB, KK, 512, nullptr);
    k_reduce_div<<<(KK * DD) / 256, 256, 0, stream>>>(Yb, 8, KK * DD, RS, aggk, SQPK);
    k_scale_cvt<<<(BB * DD) / 1024, 256, 0, stream>>>(aggn, SQPN, 256, BB * DD);
    k_scale_cvt<<<(KK * DD) / 1024, 256, 0, stream>>>(aggk, SQPK, 512, KK * DD);
  }

  // Taylor-collapsed losses
  k_loss_row<<<BB / 4, 256, 0, stream>>>(AGGN1, outAggn2, CSN, LSCN, (float)LL, LPN);
  k_loss_row<<<KK / 4, 256, 0, stream>>>(AGGK1, outAggk2, CSQ, LSCQ, (float)QQ, LPK);
  k_loss_final<<<1, 256, 0, stream>>>(LPN, BB / 4, 1.0f / BB, LPK, KK / 4, 1.0f / KK, outLoss);
}